// Round 1
// baseline (241.246 us; speedup 1.0000x reference)
//
#include <hip/hip_runtime.h>
#include <hip/hip_bf16.h>
#include <math.h>

// Problem dims
#define NB 2
#define NN 2048
#define FD 64
#define NH 4
#define NC 32
#define HIDD 128
#define ROWS_TOT (NB*NN)   // 4096

// ws layout (float offsets). Total 1,605,632 floats = 6.4 MB.
#define XP_OFF 0
#define ES_OFF (XP_OFF + ROWS_TOT*HIDD)       // 524288
#define EN_OFF (ES_OFF + ROWS_TOT*NH)         // 540672
#define CU_OFF (EN_OFF + ROWS_TOT*NH)         // 557056
#define T_OFF  (CU_OFF + ROWS_TOT*HIDD)       // 1081344

#define A_ELEMS (NB*NN*NN)                    // 8388608

// ---------------------------------------------------------------------------
// k1: xp[row][h*32+c] = x[row,:] @ kernel[:, h*32+c]; es/en per-head scores.
// 256 blocks x 128 threads, 16 rows per block. kernel matrix staged in LDS.
// ---------------------------------------------------------------------------
__global__ __launch_bounds__(128) void k1_xp(
    const float* __restrict__ x, const float* __restrict__ kern,
    const float* __restrict__ as_, const float* __restrict__ an_,
    float* __restrict__ xp, float* __restrict__ es, float* __restrict__ en)
{
  __shared__ float kmat[FD*HIDD];   // 32 KB
  __shared__ float xr[16][FD];      // 4 KB
  __shared__ float asn[HIDD], ann[HIDD];
  const int t = threadIdx.x;
  for (int i = t; i < FD*HIDD; i += 128) kmat[i] = kern[i];
  asn[t] = as_[t]; ann[t] = an_[t];
  const int row0 = blockIdx.x * 16;
  for (int i = t; i < 16*FD; i += 128) xr[i >> 6][i & 63] = x[(size_t)row0*FD + i];
  __syncthreads();
  const int h = t >> 5;
  const int c = t & 31;
  for (int r = 0; r < 16; ++r) {
    float acc = 0.f;
#pragma unroll
    for (int f = 0; f < FD; ++f) acc = fmaf(xr[r][f], kmat[f*HIDD + t], acc);
    const int grow = row0 + r;
    xp[(size_t)grow*HIDD + t] = acc;
    float s  = acc * asn[t];
    float n_ = acc * ann[t];
#pragma unroll
    for (int m = 16; m >= 1; m >>= 1) {
      s  += __shfl_xor(s, m, 32);
      n_ += __shfl_xor(n_, m, 32);
    }
    if (c == 0) { es[grow*NH + h] = s; en[grow*NH + h] = n_; }
  }
}

// ---------------------------------------------------------------------------
// k2: sparse masked softmax + aggregation. One block (256 thr) per (b,i) row.
// exp(lrelu - 1e9 - max) underflows to exactly 0 in f32, so only neighbors
// (a > 0.5) contribute — identical numerics to the dense reference.
// ---------------------------------------------------------------------------
__global__ __launch_bounds__(256) void k2_attn(
    const float* __restrict__ a, const float* __restrict__ xp,
    const float* __restrict__ es, const float* __restrict__ en,
    const float* __restrict__ bias, float* __restrict__ cu)
{
  __shared__ unsigned short sidx[NN];  // 4 KB
  __shared__ int scnt[256];            // 1 KB
  __shared__ float sw[NN*NH];          // 32 KB: per-neighbor per-head weight
  __shared__ float sred[256*NH];       // 4 KB
  __shared__ float smx[NH], ssm[NH], sesi[NH];
  __shared__ float sagg[HIDD];
  const int t = threadIdx.x;
  const int row = blockIdx.x;          // b*2048 + i
  const int b = row >> 11;

  // phase 1: scan adjacency row, count + deterministic compaction
  const float4* arow4 = (const float4*)(a + (size_t)row*NN);
  const float4 v0 = arow4[t*2], v1 = arow4[t*2+1];
  float vv[8] = {v0.x,v0.y,v0.z,v0.w,v1.x,v1.y,v1.z,v1.w};
  int cnt = 0;
#pragma unroll
  for (int q = 0; q < 8; ++q) cnt += (vv[q] > 0.5f) ? 1 : 0;
  scnt[t] = cnt;
  if (t < NH) sesi[t] = es[row*NH + t];
  __syncthreads();
  // inclusive scan (Hillis-Steele)
  for (int off = 1; off < 256; off <<= 1) {
    const int add = (t >= off) ? scnt[t - off] : 0;
    __syncthreads();
    scnt[t] += add;
    __syncthreads();
  }
  const int deg = scnt[255];
  {
    int k = scnt[t] - cnt;
    const int j0 = t * 8;
#pragma unroll
    for (int q = 0; q < 8; ++q)
      if (vv[q] > 0.5f) sidx[k++] = (unsigned short)(j0 + q);
  }
  __syncthreads();

  // phase 2: scores -> LDS, local max per head
  float lmx[NH] = {-1e30f, -1e30f, -1e30f, -1e30f};
  for (int nn = t; nn < deg; nn += 256) {
    const int j = sidx[nn];
    const float4 e4 = *(const float4*)(en + ((size_t)(b*NN + j))*NH);
    float s0 = sesi[0]+e4.x; s0 = s0 > 0.f ? s0 : 0.2f*s0;
    float s1 = sesi[1]+e4.y; s1 = s1 > 0.f ? s1 : 0.2f*s1;
    float s2 = sesi[2]+e4.z; s2 = s2 > 0.f ? s2 : 0.2f*s2;
    float s3 = sesi[3]+e4.w; s3 = s3 > 0.f ? s3 : 0.2f*s3;
    sw[nn*4+0]=s0; sw[nn*4+1]=s1; sw[nn*4+2]=s2; sw[nn*4+3]=s3;
    lmx[0]=fmaxf(lmx[0],s0); lmx[1]=fmaxf(lmx[1],s1);
    lmx[2]=fmaxf(lmx[2],s2); lmx[3]=fmaxf(lmx[3],s3);
  }
#pragma unroll
  for (int q = 0; q < 4; ++q) sred[t*4+q] = lmx[q];
  __syncthreads();
  for (int off = 128; off >= 1; off >>= 1) {
    if (t < off) {
#pragma unroll
      for (int q = 0; q < 4; ++q)
        sred[t*4+q] = fmaxf(sred[t*4+q], sred[(t+off)*4+q]);
    }
    __syncthreads();
  }
  if (t < 4) smx[t] = sred[t];
  __syncthreads();

  // phase 3: exp(score - max) -> LDS, local sum
  float lsm[NH] = {0.f, 0.f, 0.f, 0.f};
  for (int nn = t; nn < deg; nn += 256) {
#pragma unroll
    for (int q = 0; q < 4; ++q) {
      const float w = expf(sw[nn*4+q] - smx[q]);
      sw[nn*4+q] = w;
      lsm[q] += w;
    }
  }
#pragma unroll
  for (int q = 0; q < 4; ++q) sred[t*4+q] = lsm[q];
  __syncthreads();
  for (int off = 128; off >= 1; off >>= 1) {
    if (t < off) {
#pragma unroll
      for (int q = 0; q < 4; ++q)
        sred[t*4+q] += sred[(t+off)*4+q];
    }
    __syncthreads();
  }
  if (t < 4) ssm[t] = sred[t];
  __syncthreads();

  // phase 4: aggregate out[k] = sum_j w[j][h] * xp[j][k] / ssm[h] + bias[k]
  const int k = t & 127, half = t >> 7, h = k >> 5;
  float acc = 0.f;
  for (int nn = half; nn < deg; nn += 2) {
    const int j = sidx[nn];
    acc = fmaf(sw[nn*4+h], xp[((size_t)(b*NN + j))*HIDD + k], acc);
  }
  if (half) sagg[k] = acc;
  __syncthreads();
  if (!half) {
    const float tot = (acc + sagg[k]) / ssm[h] + bias[k];
    cu[(size_t)row*HIDD + k] = tot;
  }
}

// ---------------------------------------------------------------------------
// k3: fused GRU gates. 256 blocks x 256 threads, 16 rows/block.
// z = [conv_u, h] staged transposed in LDS (pad 17, conflict-free);
// u,r GEMMs (K=256), then rh in LDS, then c GEMM, epilogue h'.
// W columns read as coalesced float4 from L2.
// ---------------------------------------------------------------------------
__global__ __launch_bounds__(256) void k3_gate(
    const float* __restrict__ cu, const float* __restrict__ hin,
    const float* __restrict__ bu, const float* __restrict__ br,
    const float* __restrict__ bc, const float* __restrict__ Wu,
    const float* __restrict__ Wr, const float* __restrict__ Wc,
    float* __restrict__ hp_out)
{
  __shared__ float zT[256][17];   // 17 KB  z transposed [d][row]
  __shared__ float rhT[128][17];  // 8.5 KB r*h transposed [k][row]
  const int t = threadIdx.x;
  const int row0 = blockIdx.x * 16;
  for (int idx = t; idx < 16*256; idx += 256) {
    const int r = idx >> 8, d = idx & 255;
    const float v = (d < 128) ? cu[(size_t)(row0+r)*128 + d]
                              : hin[(size_t)(row0+r)*128 + (d-128)];
    zT[d][r] = v;
  }
  __syncthreads();
  const int k0 = (t & 31) * 4;
  const int r0 = (t >> 5) * 2;
  float au[2][4] = {{0.f}}, ar[2][4] = {{0.f}};
  for (int d = 0; d < 256; ++d) {
    const float4 wu4 = *(const float4*)(Wu + d*128 + k0);
    const float4 wr4 = *(const float4*)(Wr + d*128 + k0);
    const float* wup = (const float*)&wu4;
    const float* wrp = (const float*)&wr4;
    const float z0 = zT[d][r0], z1 = zT[d][r0+1];
#pragma unroll
    for (int q = 0; q < 4; ++q) {
      au[0][q] = fmaf(z0, wup[q], au[0][q]);
      au[1][q] = fmaf(z1, wup[q], au[1][q]);
      ar[0][q] = fmaf(z0, wrp[q], ar[0][q]);
      ar[1][q] = fmaf(z1, wrp[q], ar[1][q]);
    }
  }
  float uu[2][4], hv[2][4];
#pragma unroll
  for (int rr = 0; rr < 2; ++rr) {
    const int grow = row0 + r0 + rr;
    const int n = grow & (NN-1);
    const float bub = bu[n], brb = br[n];
#pragma unroll
    for (int q = 0; q < 4; ++q) {
      const int k = k0 + q;
      const float hval = zT[128+k][r0+rr];
      const float uv = 1.f/(1.f + expf(-(bub + au[rr][q])));
      const float rv = 1.f/(1.f + expf(-(brb + ar[rr][q])));
      uu[rr][q] = uv; hv[rr][q] = hval;
      rhT[k][r0+rr] = rv * hval;
    }
  }
  __syncthreads();
  float ac[2][4] = {{0.f}};
  for (int d = 0; d < 128; ++d) {
    const float4 wc4 = *(const float4*)(Wc + d*128 + k0);
    const float* wcp = (const float*)&wc4;
    const float z0 = zT[d][r0], z1 = zT[d][r0+1];
#pragma unroll
    for (int q = 0; q < 4; ++q) {
      ac[0][q] = fmaf(z0, wcp[q], ac[0][q]);
      ac[1][q] = fmaf(z1, wcp[q], ac[1][q]);
    }
  }
  for (int d = 0; d < 128; ++d) {
    const float4 wc4 = *(const float4*)(Wc + (128+d)*128 + k0);
    const float* wcp = (const float*)&wc4;
    const float z0 = rhT[d][r0], z1 = rhT[d][r0+1];
#pragma unroll
    for (int q = 0; q < 4; ++q) {
      ac[0][q] = fmaf(z0, wcp[q], ac[0][q]);
      ac[1][q] = fmaf(z1, wcp[q], ac[1][q]);
    }
  }
#pragma unroll
  for (int rr = 0; rr < 2; ++rr) {
    const int grow = row0 + r0 + rr;
    const int n = grow & (NN-1);
#pragma unroll
    for (int q = 0; q < 4; ++q) {
      const int k = k0 + q;
      const float cc = tanhf(bc[n] + ac[rr][q]);
      const float hpv = uu[rr][q]*hv[rr][q] + (1.f - uu[rr][q])*cc;
      hp_out[(size_t)grow*128 + k] = hpv;
    }
  }
}

// ---------------------------------------------------------------------------
// k4a: t = h' @ R_p  ([4096,128] @ [128,128])
// ---------------------------------------------------------------------------
__global__ __launch_bounds__(256) void k4a_t(
    const float* __restrict__ hp, const float* __restrict__ Rp,
    float* __restrict__ tws)
{
  __shared__ float hrow[16][128];
  const int t = threadIdx.x;
  const int row0 = blockIdx.x * 16;
  for (int idx = t; idx < 16*128; idx += 256)
    hrow[idx >> 7][idx & 127] = hp[(size_t)row0*128 + idx];
  __syncthreads();
  const int k = t & 127, rq = t >> 7;
  float acc[8] = {0.f};
  for (int d = 0; d < 128; ++d) {
    const float rv = Rp[d*128 + k];
#pragma unroll
    for (int rr = 0; rr < 8; ++rr)
      acc[rr] = fmaf(hrow[rq*8+rr][d], rv, acc[rr]);
  }
#pragma unroll
  for (int rr = 0; rr < 8; ++rr)
    tws[(size_t)(row0 + rq*8 + rr)*128 + k] = acc[rr];
}

// ---------------------------------------------------------------------------
// k4b: A[b] = t[b] @ hp[b]^T  (2048x128 @ 128x2048 per batch)
// 64x64 tile, K-chunks of 64, both operands transposed in LDS (pad 68)
// so inner loop = 2x ds_read_b128 + 16 FMA.
// ---------------------------------------------------------------------------
__global__ __launch_bounds__(256) void k4b_dec(
    const float* __restrict__ t_, const float* __restrict__ hp,
    float* __restrict__ A)
{
  __shared__ float taT[64][68];   // [k][i], 17.4 KB
  __shared__ float hbT[64][68];   // [k][j], 17.4 KB
  const int tt = threadIdx.x;
  const int b = blockIdx.z;
  const int i0 = blockIdx.y * 64, j0 = blockIdx.x * 64;
  const int tx = tt & 15, ty = tt >> 4;
  float acc[4][4] = {{0.f}};
  for (int kc = 0; kc < 128; kc += 64) {
    __syncthreads();
    for (int q = tt; q < 1024; q += 256) {
      const int r = q >> 4;
      const int kk = (q & 15) * 4;
      const float4 v = *(const float4*)(t_ + ((size_t)(b*NN) + i0 + r)*128 + kc + kk);
      taT[kk+0][r] = v.x; taT[kk+1][r] = v.y; taT[kk+2][r] = v.z; taT[kk+3][r] = v.w;
      const float4 w = *(const float4*)(hp + ((size_t)(b*NN) + j0 + r)*128 + kc + kk);
      hbT[kk+0][r] = w.x; hbT[kk+1][r] = w.y; hbT[kk+2][r] = w.z; hbT[kk+3][r] = w.w;
    }
    __syncthreads();
    for (int kk = 0; kk < 64; ++kk) {
      const float4 av = *(const float4*)&taT[kk][4*ty];
      const float4 bv = *(const float4*)&hbT[kk][4*tx];
      acc[0][0]=fmaf(av.x,bv.x,acc[0][0]); acc[0][1]=fmaf(av.x,bv.y,acc[0][1]);
      acc[0][2]=fmaf(av.x,bv.z,acc[0][2]); acc[0][3]=fmaf(av.x,bv.w,acc[0][3]);
      acc[1][0]=fmaf(av.y,bv.x,acc[1][0]); acc[1][1]=fmaf(av.y,bv.y,acc[1][1]);
      acc[1][2]=fmaf(av.y,bv.z,acc[1][2]); acc[1][3]=fmaf(av.y,bv.w,acc[1][3]);
      acc[2][0]=fmaf(av.z,bv.x,acc[2][0]); acc[2][1]=fmaf(av.z,bv.y,acc[2][1]);
      acc[2][2]=fmaf(av.z,bv.z,acc[2][2]); acc[2][3]=fmaf(av.z,bv.w,acc[2][3]);
      acc[3][0]=fmaf(av.w,bv.x,acc[3][0]); acc[3][1]=fmaf(av.w,bv.y,acc[3][1]);
      acc[3][2]=fmaf(av.w,bv.z,acc[3][2]); acc[3][3]=fmaf(av.w,bv.w,acc[3][3]);
    }
  }
#pragma unroll
  for (int di = 0; di < 4; ++di) {
    const float4 o = make_float4(acc[di][0], acc[di][1], acc[di][2], acc[di][3]);
    *(float4*)(A + ((size_t)(b*NN) + i0 + 4*ty + di)*NN + j0 + 4*tx) = o;
  }
}

// ---------------------------------------------------------------------------
extern "C" void kernel_launch(void* const* d_in, const int* in_sizes, int n_in,
                              void* d_out, int out_size, void* d_ws, size_t ws_size,
                              hipStream_t stream)
{
  const float* x    = (const float*)d_in[0];
  const float* a    = (const float*)d_in[1];
  const float* h    = (const float*)d_in[2];
  const float* kern = (const float*)d_in[3];
  const float* as_  = (const float*)d_in[4];
  const float* an_  = (const float*)d_in[5];
  const float* bias = (const float*)d_in[6];
  const float* bu   = (const float*)d_in[7];
  const float* br   = (const float*)d_in[8];
  const float* bc   = (const float*)d_in[9];
  const float* Wu   = (const float*)d_in[10];
  const float* Wr   = (const float*)d_in[11];
  const float* Wc   = (const float*)d_in[12];
  const float* Rp   = (const float*)d_in[13];
  (void)in_sizes; (void)n_in; (void)out_size; (void)ws_size;

  float* ws = (float*)d_ws;
  float* xp = ws + XP_OFF;
  float* es = ws + ES_OFF;
  float* en = ws + EN_OFF;
  float* cu = ws + CU_OFF;
  float* tw = ws + T_OFF;

  float* A  = (float*)d_out;
  float* hp = (float*)d_out + A_ELEMS;

  hipLaunchKernelGGL(k1_xp,   dim3(ROWS_TOT/16), dim3(128), 0, stream,
                     x, kern, as_, an_, xp, es, en);
  hipLaunchKernelGGL(k2_attn, dim3(ROWS_TOT), dim3(256), 0, stream,
                     a, xp, es, en, bias, cu);
  hipLaunchKernelGGL(k3_gate, dim3(ROWS_TOT/16), dim3(256), 0, stream,
                     cu, h, bu, br, bc, Wu, Wr, Wc, hp);
  hipLaunchKernelGGL(k4a_t,   dim3(ROWS_TOT/16), dim3(256), 0, stream,
                     hp, Rp, tw);
  hipLaunchKernelGGL(k4b_dec, dim3(NN/64, NN/64, NB), dim3(256), 0, stream,
                     tw, hp, A);
}

// Round 4
// 162.752 us; speedup vs baseline: 1.4823x; 1.4823x over previous
//
#include <hip/hip_runtime.h>
#include <hip/hip_bf16.h>
#include <math.h>

// Problem dims
#define NB 2
#define NN 2048
#define FD 64
#define NH 4
#define HIDD 128
#define ROWS_TOT (NB*NN)   // 4096

// ws layout (float offsets). Total 1,605,632 floats = 6.4 MB (same as r1).
#define XP_OFF   0
#define ES_OFF   524288
#define EN_OFF   540672
#define CU_OFF   557056
#define TBF_OFF  1081344   // bf16 t  [4096][128] (262144 floats)
#define HPBF_OFF 1343488   // bf16 h' [4096][128]

#define A_ELEMS (NB*NN*NN)

typedef __attribute__((ext_vector_type(8))) short bf16x8;
typedef __attribute__((ext_vector_type(8))) unsigned short ushort8;
typedef __attribute__((ext_vector_type(4))) float f32x4;

// ---------------------------------------------------------------------------
// k1: xp = x @ kernel (per-head), plus per-head scores es/en.
// 512 blocks x 256 thr, 8 rows/block, 4 rows/thread (ILP), kernel streamed
// from L2 (no LDS stage). col = h*32+c.
// ---------------------------------------------------------------------------
__global__ __launch_bounds__(256) void k1_xp(
    const float* __restrict__ x, const float* __restrict__ kern,
    const float* __restrict__ as_, const float* __restrict__ an_,
    float* __restrict__ xp, float* __restrict__ es, float* __restrict__ en)
{
  __shared__ float xr[8][FD];
  const int t = threadIdx.x;
  const int col = t & 127, rg = t >> 7;     // rg in {0,1}: rows rg*4..rg*4+3
  const int row0 = blockIdx.x * 8;
  for (int idx = t; idx < 8*FD; idx += 256)
    xr[idx >> 6][idx & 63] = x[(size_t)row0*FD + idx];
  __syncthreads();
  const float asv = as_[col], anv = an_[col];
  float acc[4] = {0.f, 0.f, 0.f, 0.f};
  for (int f = 0; f < FD; ++f) {
    const float kv = kern[f*128 + col];
#pragma unroll
    for (int rr = 0; rr < 4; ++rr)
      acc[rr] = fmaf(xr[rg*4 + rr][f], kv, acc[rr]);
  }
  const int h = col >> 5;
  const int c = col & 31;
#pragma unroll
  for (int rr = 0; rr < 4; ++rr) {
    const int grow = row0 + rg*4 + rr;
    xp[(size_t)grow*128 + col] = acc[rr];
    float s = acc[rr]*asv, n_ = acc[rr]*anv;
#pragma unroll
    for (int mk = 16; mk >= 1; mk >>= 1) {
      s  += __shfl_xor(s,  mk, 32);
      n_ += __shfl_xor(n_, mk, 32);
    }
    if (c == 0) { es[grow*NH + h] = s; en[grow*NH + h] = n_; }
  }
}

// ---------------------------------------------------------------------------
// k2: sparse masked softmax + aggregation, wave-per-row, ZERO block barriers.
// 1024 blocks x 256 thr = 4 waves, each wave owns one (b,i) row.
// Ballot-compaction of the adjacency row, then flash-style online softmax
// over 64-neighbor chunks. exp underflow makes this exactly equal to the
// dense reference.
// ---------------------------------------------------------------------------
__global__ __launch_bounds__(256) void k2_attn(
    const float* __restrict__ a, const float* __restrict__ xp,
    const float* __restrict__ es, const float* __restrict__ en,
    const float* __restrict__ bias, float* __restrict__ cu)
{
  __shared__ unsigned short sidx[4][NN];   // 16 KB
  __shared__ float swl[4][64][NH];         // 4 KB
  const int t = threadIdx.x;
  const int ln = t & 63, wv = t >> 6;
  const int row = blockIdx.x * 4 + wv;     // b*2048 + i
  const int b = row >> 11;
  const float4 esi = *(const float4*)(es + (size_t)row*NH);

  // --- wave-local deterministic compaction via ballot ---
  int deg = 0;
  const float4* arow4 = (const float4*)(a + (size_t)row*NN);
#pragma unroll
  for (int cch = 0; cch < 8; ++cch) {
    const float4 v = arow4[cch*64 + ln];
    const int j0 = cch*256 + ln*4;
    const float vv[4] = {v.x, v.y, v.z, v.w};
#pragma unroll
    for (int q = 0; q < 4; ++q) {
      const unsigned long long m = __ballot(vv[q] > 0.5f);
      if (vv[q] > 0.5f) {
        const int pos = deg + (int)__popcll(m & ((1ull << ln) - 1ull));
        sidx[wv][pos] = (unsigned short)(j0 + q);
      }
      deg += (int)__popcll(m);
    }
  }

  // --- flash-style online softmax + aggregate ---
  const int col0 = ln, col1 = ln + 64;
  const int h0 = ln >> 5;                  // head of col0 (0/1); col1 head = h0+2
  float m0=-1e30f, m1=-1e30f, m2=-1e30f, m3=-1e30f;
  float s0=0.f, s1=0.f, s2=0.f, s3=0.f;
  float acc0=0.f, acc1=0.f;
  for (int base = 0; base < deg; base += 64) {
    const int rem = min(64, deg - base);
    float t0=-1e30f, t1=-1e30f, t2=-1e30f, t3=-1e30f;
    if (ln < rem) {
      const int j = sidx[wv][base + ln];
      const float4 e4 = *(const float4*)(en + (size_t)(b*NN + j)*NH);
      t0 = esi.x + e4.x; t0 = t0 > 0.f ? t0 : 0.2f*t0;
      t1 = esi.y + e4.y; t1 = t1 > 0.f ? t1 : 0.2f*t1;
      t2 = esi.z + e4.z; t2 = t2 > 0.f ? t2 : 0.2f*t2;
      t3 = esi.w + e4.w; t3 = t3 > 0.f ? t3 : 0.2f*t3;
    }
    float c0=t0, c1=t1, c2=t2, c3=t3;
#pragma unroll
    for (int mk = 32; mk >= 1; mk >>= 1) {
      c0 = fmaxf(c0, __shfl_xor(c0, mk));
      c1 = fmaxf(c1, __shfl_xor(c1, mk));
      c2 = fmaxf(c2, __shfl_xor(c2, mk));
      c3 = fmaxf(c3, __shfl_xor(c3, mk));
    }
    const float nm0 = fmaxf(m0,c0), nm1 = fmaxf(m1,c1);
    const float nm2 = fmaxf(m2,c2), nm3 = fmaxf(m3,c3);
    const float r0 = expf(m0-nm0), r1 = expf(m1-nm1);
    const float r2 = expf(m2-nm2), r3 = expf(m3-nm3);
    s0 *= r0; s1 *= r1; s2 *= r2; s3 *= r3;
    float w0=0.f, w1=0.f, w2=0.f, w3=0.f;
    if (ln < rem) {
      w0 = expf(t0-nm0); w1 = expf(t1-nm1);
      w2 = expf(t2-nm2); w3 = expf(t3-nm3);
    }
    float u0=w0, u1=w1, u2=w2, u3=w3;
#pragma unroll
    for (int mk = 32; mk >= 1; mk >>= 1) {
      u0 += __shfl_xor(u0, mk);
      u1 += __shfl_xor(u1, mk);
      u2 += __shfl_xor(u2, mk);
      u3 += __shfl_xor(u3, mk);
    }
    s0 += u0; s1 += u1; s2 += u2; s3 += u3;
    acc0 *= (h0 ? r1 : r0);
    acc1 *= (h0 ? r3 : r2);
    swl[wv][ln][0] = w0; swl[wv][ln][1] = w1;
    swl[wv][ln][2] = w2; swl[wv][ln][3] = w3;
#pragma unroll 4
    for (int k = 0; k < rem; ++k) {
      const int j = sidx[wv][base + k];
      const float* xr = xp + (size_t)(b*NN + j)*128;
      acc0 = fmaf(swl[wv][k][h0],     xr[col0], acc0);
      acc1 = fmaf(swl[wv][k][2 + h0], xr[col1], acc1);
    }
    m0=nm0; m1=nm1; m2=nm2; m3=nm3;
  }
  const float den0 = h0 ? s1 : s0;
  const float den1 = h0 ? s3 : s2;
  cu[(size_t)row*128 + col0] = acc0/den0 + bias[col0];
  cu[(size_t)row*128 + col1] = acc1/den1 + bias[col1];
}

// ---------------------------------------------------------------------------
// k3: fused GRU gates + t = h'@R_p. 256 blocks x 512 thr, 16 rows/block,
// 4 rows/thread. z staged transposed (pad 17). Emits f32 h' (output),
// bf16 h' and bf16 t for the MFMA decoder.
// ---------------------------------------------------------------------------
__global__ __launch_bounds__(512) void k3_gate(
    const float* __restrict__ cu_, const float* __restrict__ hin,
    const float* __restrict__ bu, const float* __restrict__ br,
    const float* __restrict__ bc, const float* __restrict__ Wu,
    const float* __restrict__ Wr, const float* __restrict__ Wc,
    const float* __restrict__ Rp, float* __restrict__ hp_out,
    __hip_bfloat16* __restrict__ hp_bf, __hip_bfloat16* __restrict__ t_bf)
{
  __shared__ float zT[256][17];   // z transposed [d][row]
  __shared__ float rhT[128][17];  // r*h transposed
  __shared__ float hpL[16][128];  // h' rows for the t-GEMM
  const int t = threadIdx.x;
  const int col = t & 127, rg = t >> 7;   // rg 0..3 -> rows rg*4..rg*4+3
  const int row0 = blockIdx.x * 16;
  for (int idx = t; idx < 16*256; idx += 512) {
    const int r = idx >> 8, d = idx & 255;
    zT[d][r] = (d < 128) ? cu_[(size_t)(row0+r)*128 + d]
                         : hin[(size_t)(row0+r)*128 + (d-128)];
  }
  __syncthreads();
  float au[4] = {0.f,0.f,0.f,0.f}, ar[4] = {0.f,0.f,0.f,0.f};
  for (int d = 0; d < 256; ++d) {
    const float wu = Wu[d*128 + col];
    const float wr = Wr[d*128 + col];
#pragma unroll
    for (int rr = 0; rr < 4; ++rr) {
      const float z = zT[d][rg*4 + rr];
      au[rr] = fmaf(z, wu, au[rr]);
      ar[rr] = fmaf(z, wr, ar[rr]);
    }
  }
  float uu[4], hv[4];
#pragma unroll
  for (int rr = 0; rr < 4; ++rr) {
    const int r = rg*4 + rr;
    const int n = (row0 + r) & (NN-1);
    hv[rr] = zT[128 + col][r];
    uu[rr] = 1.f/(1.f + expf(-(bu[n] + au[rr])));
    const float rv = 1.f/(1.f + expf(-(br[n] + ar[rr])));
    rhT[col][r] = rv * hv[rr];
  }
  __syncthreads();
  float ac[4] = {0.f,0.f,0.f,0.f};
  for (int d = 0; d < 128; ++d) {
    const float wc1 = Wc[d*128 + col];
    const float wc2 = Wc[(128 + d)*128 + col];
#pragma unroll
    for (int rr = 0; rr < 4; ++rr) {
      ac[rr] = fmaf(zT[d][rg*4+rr],  wc1, ac[rr]);
      ac[rr] = fmaf(rhT[d][rg*4+rr], wc2, ac[rr]);
    }
  }
#pragma unroll
  for (int rr = 0; rr < 4; ++rr) {
    const int r = rg*4 + rr;
    const int grow = row0 + r;
    const int n = grow & (NN-1);
    const float cc = tanhf(bc[n] + ac[rr]);
    const float hpv = uu[rr]*hv[rr] + (1.f - uu[rr])*cc;
    hp_out[(size_t)grow*128 + col] = hpv;
    hp_bf[(size_t)grow*128 + col] = __float2bfloat16(hpv);
    hpL[r][col] = hpv;
  }
  __syncthreads();
  float tacc[4] = {0.f,0.f,0.f,0.f};
  for (int d = 0; d < 128; ++d) {
    const float rv = Rp[d*128 + col];
#pragma unroll
    for (int rr = 0; rr < 4; ++rr)
      tacc[rr] = fmaf(hpL[rg*4+rr][d], rv, tacc[rr]);
  }
#pragma unroll
  for (int rr = 0; rr < 4; ++rr)
    t_bf[(size_t)(row0 + rg*4 + rr)*128 + col] = __float2bfloat16(tacc[rr]);
}

// ---------------------------------------------------------------------------
// k4b: A[b] = t[b] @ hp[b]^T via bf16 MFMA 16x16x32. 128x128 tile, K=128
// staged once in LDS (both tiles, XOR-swizzled rows: byte ^= (row&7)<<4,
// applied on ds_write AND ds_read). 4 waves (2x2), 64x64 per wave.
// A-frag: row=lane&15, k=(lane>>4)*8+e. B-frag: col=lane&15, same k.
// C/D: col=lane&15, row=(lane>>4)*4+reg (m89-verified layout).
// ---------------------------------------------------------------------------
__global__ __launch_bounds__(256) void k4b_dec(
    const __hip_bfloat16* __restrict__ t_bf,
    const __hip_bfloat16* __restrict__ hp_bf,
    float* __restrict__ A)
{
  __shared__ __align__(16) char Alds[128*256];  // 32 KB
  __shared__ __align__(16) char Blds[128*256];  // 32 KB
  const int t = threadIdx.x;
  const int ln = t & 63, wv = t >> 6;
  const int b = blockIdx.z;
  const int i0 = blockIdx.y * 128, j0 = blockIdx.x * 128;

  // stage both 128x128 bf16 tiles, swizzled on the write side
  {
    const int sub = ln >> 4;           // 0..3
    const int cb  = (ln & 15) * 16;    // byte offset within 256B row
#pragma unroll
    for (int q = 0; q < 8; ++q) {
      const int chunk = wv*8 + q;      // 0..31
      const int row = chunk*4 + sub;   // 0..127
      const int scb = cb ^ ((row & 7) << 4);
      const ushort8 va = *(const ushort8*)
          ((const char*)(t_bf + ((size_t)(b*NN) + i0 + row)*128) + cb);
      *(ushort8*)(Alds + row*256 + scb) = va;
      const ushort8 vb = *(const ushort8*)
          ((const char*)(hp_bf + ((size_t)(b*NN) + j0 + row)*128) + cb);
      *(ushort8*)(Blds + row*256 + scb) = vb;
    }
  }
  __syncthreads();

  const int wr = wv >> 1, wc = wv & 1;  // 2x2 wave grid, 64x64 each
  const int lrow = ln & 15;
  const int kid  = ln >> 4;             // 0..3
  f32x4 acc[4][4];
  const f32x4 zero = {0.f, 0.f, 0.f, 0.f};
#pragma unroll
  for (int m = 0; m < 4; ++m)
#pragma unroll
    for (int n = 0; n < 4; ++n) acc[m][n] = zero;

#pragma unroll
  for (int ks = 0; ks < 4; ++ks) {
    const int kb = ks*64 + kid*16;      // byte offset of this lane's k-slice
    bf16x8 af[4], bfr[4];
#pragma unroll
    for (int m = 0; m < 4; ++m) {
      const int arow = wr*64 + m*16 + lrow;
      af[m] = *(const bf16x8*)(Alds + arow*256 + (kb ^ ((arow & 7) << 4)));
      const int brow = wc*64 + m*16 + lrow;
      bfr[m] = *(const bf16x8*)(Blds + brow*256 + (kb ^ ((brow & 7) << 4)));
    }
#pragma unroll
    for (int m = 0; m < 4; ++m)
#pragma unroll
      for (int n = 0; n < 4; ++n)
        acc[m][n] = __builtin_amdgcn_mfma_f32_16x16x32_bf16(
            af[m], bfr[n], acc[m][n], 0, 0, 0);
  }

#pragma unroll
  for (int m = 0; m < 4; ++m) {
    const int grow = i0 + wr*64 + m*16 + (ln >> 4)*4;
#pragma unroll
    for (int n = 0; n < 4; ++n) {
      const int gcol = j0 + wc*64 + n*16 + (ln & 15);
      float* Ap = A + ((size_t)b*NN + grow)*NN + gcol;
#pragma unroll
      for (int r = 0; r < 4; ++r)
        Ap[(size_t)r*NN] = acc[m][n][r];
    }
  }
}

// ---------------------------------------------------------------------------
extern "C" void kernel_launch(void* const* d_in, const int* in_sizes, int n_in,
                              void* d_out, int out_size, void* d_ws, size_t ws_size,
                              hipStream_t stream)
{
  const float* x    = (const float*)d_in[0];
  const float* a    = (const float*)d_in[1];
  const float* h    = (const float*)d_in[2];
  const float* kern = (const float*)d_in[3];
  const float* as_  = (const float*)d_in[4];
  const float* an_  = (const float*)d_in[5];
  const float* bias = (const float*)d_in[6];
  const float* bu   = (const float*)d_in[7];
  const float* br   = (const float*)d_in[8];
  const float* bc   = (const float*)d_in[9];
  const float* Wu   = (const float*)d_in[10];
  const float* Wr   = (const float*)d_in[11];
  const float* Wc   = (const float*)d_in[12];
  const float* Rp   = (const float*)d_in[13];
  (void)in_sizes; (void)n_in; (void)out_size; (void)ws_size;

  float* ws = (float*)d_ws;
  float* xp = ws + XP_OFF;
  float* es = ws + ES_OFF;
  float* en = ws + EN_OFF;
  float* cu = ws + CU_OFF;
  __hip_bfloat16* t_bf  = (__hip_bfloat16*)(ws + TBF_OFF);
  __hip_bfloat16* hp_bf = (__hip_bfloat16*)(ws + HPBF_OFF);

  float* A  = (float*)d_out;
  float* hp = (float*)d_out + A_ELEMS;

  hipLaunchKernelGGL(k1_xp,   dim3(ROWS_TOT/8), dim3(256), 0, stream,
                     x, kern, as_, an_, xp, es, en);
  hipLaunchKernelGGL(k2_attn, dim3(ROWS_TOT/4), dim3(256), 0, stream,
                     a, xp, es, en, bias, cu);
  hipLaunchKernelGGL(k3_gate, dim3(ROWS_TOT/16), dim3(512), 0, stream,
                     cu, h, bu, br, bc, Wu, Wr, Wc, Rp, hp, hp_bf, t_bf);
  hipLaunchKernelGGL(k4b_dec, dim3(NN/128, NN/128, NB), dim3(256), 0, stream,
                     t_bf, hp_bf, A);
}

// Round 9
// 153.288 us; speedup vs baseline: 1.5738x; 1.0617x over previous
//
#include <hip/hip_runtime.h>
#include <hip/hip_bf16.h>
#include <math.h>

// Problem dims
#define NB 2
#define NN 2048
#define FD 64
#define NH 4
#define HIDD 128
#define ROWS_TOT (NB*NN)   // 4096

// ws layout (float offsets). Total 1,720,320 floats = 6.88 MB.
#define XP_OFF   0
#define ES_OFF   524288
#define EN_OFF   540672
#define CU_OFF   557056
#define TBF_OFF  1081344   // bf16 t  [4096][128]
#define HPBF_OFF 1343488   // bf16 h' [4096][128]
// prep: transposed bf16 hi/lo weights
#define WUH_OFF  1605632   // [128][256] bf16 = 16384 floats each
#define WUL_OFF  1622016
#define WRH_OFF  1638400
#define WRL_OFF  1654784
#define WCH_OFF  1671168
#define WCL_OFF  1687552
#define RPH_OFF  1703936   // [128][128] bf16 = 8192 floats each
#define RPL_OFF  1712128

#define A_ELEMS (NB*NN*NN)

typedef __attribute__((ext_vector_type(8))) short bf16x8;
typedef __attribute__((ext_vector_type(8))) unsigned short ushort8;
typedef __attribute__((ext_vector_type(4))) unsigned short ushort4v;
typedef __attribute__((ext_vector_type(4))) float f32x4;

#define MFMA_BF16(a,b,c) __builtin_amdgcn_mfma_f32_16x16x32_bf16((a),(b),(c),0,0,0)

static __device__ inline unsigned short f2bf(float x) {
  __hip_bfloat16 b = __float2bfloat16(x);
  unsigned short u; __builtin_memcpy(&u, &b, 2); return u;
}
static __device__ inline float bf2f(unsigned short u) {
  __hip_bfloat16 b; __builtin_memcpy(&b, &u, 2); return __bfloat162float(b);
}
static __device__ inline void split2(float x, unsigned short& hi, unsigned short& lo) {
  hi = f2bf(x);
  lo = f2bf(x - bf2f(hi));
}

// ---------------------------------------------------------------------------
// k0: prep — transpose + hi/lo bf16 split of Wu, Wr, Wc ([256][128] ->
// [128][256]) and Rp ([128][128] -> [128][128]). One-time, tiny.
// ---------------------------------------------------------------------------
__global__ __launch_bounds__(256) void k0_prep(
    const float* __restrict__ Wu, const float* __restrict__ Wr,
    const float* __restrict__ Wc, const float* __restrict__ Rp,
    unsigned short* __restrict__ wuh, unsigned short* __restrict__ wul,
    unsigned short* __restrict__ wrh, unsigned short* __restrict__ wrl,
    unsigned short* __restrict__ wch, unsigned short* __restrict__ wcl,
    unsigned short* __restrict__ rph, unsigned short* __restrict__ rpl)
{
  const int gid = blockIdx.x*256 + threadIdx.x;
  if (gid < 98304) {
    const int which = gid >> 15;          // 0,1,2
    const int loc = gid & 32767;
    const int j = loc >> 8, k = loc & 255;
    const float* W = which == 0 ? Wu : (which == 1 ? Wr : Wc);
    unsigned short* oh = which == 0 ? wuh : (which == 1 ? wrh : wch);
    unsigned short* ol = which == 0 ? wul : (which == 1 ? wrl : wcl);
    unsigned short h, l; split2(W[k*128 + j], h, l);
    oh[loc] = h; ol[loc] = l;
  } else if (gid < 114688) {
    const int loc = gid - 98304;
    const int j = loc >> 7, k = loc & 127;
    unsigned short h, l; split2(Rp[k*128 + j], h, l);
    rph[loc] = h; rpl[loc] = l;
  }
}

// ---------------------------------------------------------------------------
// k1: xp = x @ kernel, plus per-head scores es/en. 512 blocks x 256 thr,
// 8 rows/block; thread = (row rq, 4 cols c4); float4 kern loads (coalesced,
// L2-resident); 8-lane head-local shuffle reduction for es/en.
// ---------------------------------------------------------------------------
__global__ __launch_bounds__(256) void k1_xp(
    const float* __restrict__ x, const float* __restrict__ kern,
    const float* __restrict__ as_, const float* __restrict__ an_,
    float* __restrict__ xp, float* __restrict__ es, float* __restrict__ en)
{
  __shared__ float xr[8][FD];
  const int t = threadIdx.x;
  const int row0 = blockIdx.x * 8;
  for (int idx = t; idx < 8*FD; idx += 256)
    xr[idx >> 6][idx & 63] = x[(size_t)row0*FD + idx];
  __syncthreads();
  const int c4 = (t & 31) * 4;       // cols c4..c4+3
  const int rq = t >> 5;             // row 0..7
  const float4 asv = *(const float4*)(as_ + c4);
  const float4 anv = *(const float4*)(an_ + c4);
  float4 acc = make_float4(0.f, 0.f, 0.f, 0.f);
  for (int f = 0; f < FD; ++f) {
    const float4 kv = *(const float4*)(kern + f*128 + c4);
    const float xv = xr[rq][f];
    acc.x = fmaf(xv, kv.x, acc.x);
    acc.y = fmaf(xv, kv.y, acc.y);
    acc.z = fmaf(xv, kv.z, acc.z);
    acc.w = fmaf(xv, kv.w, acc.w);
  }
  const int grow = row0 + rq;
  *(float4*)(xp + (size_t)grow*128 + c4) = acc;
  float s  = acc.x*asv.x + acc.y*asv.y + acc.z*asv.z + acc.w*asv.w;
  float n_ = acc.x*anv.x + acc.y*anv.y + acc.z*anv.z + acc.w*anv.w;
#pragma unroll
  for (int mk = 4; mk >= 1; mk >>= 1) {
    s  += __shfl_xor(s,  mk, 64);
    n_ += __shfl_xor(n_, mk, 64);
  }
  if ((t & 7) == 0) {
    const int h = (t & 31) >> 3;
    es[grow*NH + h] = s; en[grow*NH + h] = n_;
  }
}

// ---------------------------------------------------------------------------
// k2: sparse masked softmax + aggregation, wave-per-row, ZERO block barriers.
// (unchanged from round 4 — hardware-verified)
// ---------------------------------------------------------------------------
__global__ __launch_bounds__(256) void k2_attn(
    const float* __restrict__ a, const float* __restrict__ xp,
    const float* __restrict__ es, const float* __restrict__ en,
    const float* __restrict__ bias, float* __restrict__ cu)
{
  __shared__ unsigned short sidx[4][NN];   // 16 KB
  __shared__ float swl[4][64][NH];         // 4 KB
  const int t = threadIdx.x;
  const int ln = t & 63, wv = t >> 6;
  const int row = blockIdx.x * 4 + wv;     // b*2048 + i
  const int b = row >> 11;
  const float4 esi = *(const float4*)(es + (size_t)row*NH);

  int deg = 0;
  const float4* arow4 = (const float4*)(a + (size_t)row*NN);
#pragma unroll
  for (int cch = 0; cch < 8; ++cch) {
    const float4 v = arow4[cch*64 + ln];
    const int j0 = cch*256 + ln*4;
    const float vv[4] = {v.x, v.y, v.z, v.w};
#pragma unroll
    for (int q = 0; q < 4; ++q) {
      const unsigned long long m = __ballot(vv[q] > 0.5f);
      if (vv[q] > 0.5f) {
        const int pos = deg + (int)__popcll(m & ((1ull << ln) - 1ull));
        sidx[wv][pos] = (unsigned short)(j0 + q);
      }
      deg += (int)__popcll(m);
    }
  }

  const int col0 = ln, col1 = ln + 64;
  const int h0 = ln >> 5;
  float m0=-1e30f, m1=-1e30f, m2=-1e30f, m3=-1e30f;
  float s0=0.f, s1=0.f, s2=0.f, s3=0.f;
  float acc0=0.f, acc1=0.f;
  for (int base = 0; base < deg; base += 64) {
    const int rem = min(64, deg - base);
    float t0=-1e30f, t1=-1e30f, t2=-1e30f, t3=-1e30f;
    if (ln < rem) {
      const int j = sidx[wv][base + ln];
      const float4 e4 = *(const float4*)(en + (size_t)(b*NN + j)*NH);
      t0 = esi.x + e4.x; t0 = t0 > 0.f ? t0 : 0.2f*t0;
      t1 = esi.y + e4.y; t1 = t1 > 0.f ? t1 : 0.2f*t1;
      t2 = esi.z + e4.z; t2 = t2 > 0.f ? t2 : 0.2f*t2;
      t3 = esi.w + e4.w; t3 = t3 > 0.f ? t3 : 0.2f*t3;
    }
    float c0=t0, c1=t1, c2=t2, c3=t3;
#pragma unroll
    for (int mk = 32; mk >= 1; mk >>= 1) {
      c0 = fmaxf(c0, __shfl_xor(c0, mk));
      c1 = fmaxf(c1, __shfl_xor(c1, mk));
      c2 = fmaxf(c2, __shfl_xor(c2, mk));
      c3 = fmaxf(c3, __shfl_xor(c3, mk));
    }
    const float nm0 = fmaxf(m0,c0), nm1 = fmaxf(m1,c1);
    const float nm2 = fmaxf(m2,c2), nm3 = fmaxf(m3,c3);
    const float r0 = expf(m0-nm0), r1 = expf(m1-nm1);
    const float r2 = expf(m2-nm2), r3 = expf(m3-nm3);
    s0 *= r0; s1 *= r1; s2 *= r2; s3 *= r3;
    float w0=0.f, w1=0.f, w2=0.f, w3=0.f;
    if (ln < rem) {
      w0 = expf(t0-nm0); w1 = expf(t1-nm1);
      w2 = expf(t2-nm2); w3 = expf(t3-nm3);
    }
    float u0=w0, u1=w1, u2=w2, u3=w3;
#pragma unroll
    for (int mk = 32; mk >= 1; mk >>= 1) {
      u0 += __shfl_xor(u0, mk);
      u1 += __shfl_xor(u1, mk);
      u2 += __shfl_xor(u2, mk);
      u3 += __shfl_xor(u3, mk);
    }
    s0 += u0; s1 += u1; s2 += u2; s3 += u3;
    acc0 *= (h0 ? r1 : r0);
    acc1 *= (h0 ? r3 : r2);
    swl[wv][ln][0] = w0; swl[wv][ln][1] = w1;
    swl[wv][ln][2] = w2; swl[wv][ln][3] = w3;
#pragma unroll 4
    for (int k = 0; k < rem; ++k) {
      const int j = sidx[wv][base + k];
      const float* xr = xp + (size_t)(b*NN + j)*128;
      acc0 = fmaf(swl[wv][k][h0],     xr[col0], acc0);
      acc1 = fmaf(swl[wv][k][2 + h0], xr[col1], acc1);
    }
    m0=nm0; m1=nm1; m2=nm2; m3=nm3;
  }
  const float den0 = h0 ? s1 : s0;
  const float den1 = h0 ? s3 : s2;
  cu[(size_t)row*128 + col0] = acc0/den0 + bias[col0];
  cu[(size_t)row*128 + col1] = acc1/den1 + bias[col1];
}

// ---------------------------------------------------------------------------
// k3: fused GRU gates + t = h'@R_p, all GEMMs via 3-term split-bf16 MFMA
// (f32-accurate). 256 blocks x 256 thr (4 waves), 16 rows/block; wave w
// owns cols [w*32, w*32+32) = 2 N-tiles. W operands read as B-frags
// straight from L2 (pre-transposed hi/lo bf16 from k0). LDS tiles use the
// verified (row&7)<<4 XOR swizzle on both write and read sides.
// ---------------------------------------------------------------------------
__global__ __launch_bounds__(256) void k3_mfma(
    const float* __restrict__ cu_, const float* __restrict__ hin,
    const float* __restrict__ bu, const float* __restrict__ br,
    const float* __restrict__ bc,
    const unsigned short* __restrict__ wuh, const unsigned short* __restrict__ wul,
    const unsigned short* __restrict__ wrh, const unsigned short* __restrict__ wrl,
    const unsigned short* __restrict__ wch, const unsigned short* __restrict__ wcl,
    const unsigned short* __restrict__ rph, const unsigned short* __restrict__ rpl,
    float* __restrict__ hp_out,
    __hip_bfloat16* __restrict__ hp_bf, __hip_bfloat16* __restrict__ t_bf)
{
  __shared__ __align__(16) char zH[16*512];   // z hi  [16][256] bf16, 8 KB
  __shared__ __align__(16) char zL[16*512];   // z lo
  __shared__ __align__(16) char rhH[16*256];  // r*h hi [16][128] bf16, 4 KB
  __shared__ __align__(16) char rhL[16*256];
  __shared__ __align__(16) char hpH[16*256];  // h' hi
  __shared__ __align__(16) char hpLo[16*256];
  const int t = threadIdx.x;
  const int row0 = blockIdx.x * 16;

  // ---- stage z = [cu | h] as split bf16, swizzled ----
#pragma unroll
  for (int i = 0; i < 4; ++i) {
    const int q = t + 256*i;           // float4 id 0..1023
    const int r = q >> 6;              // row 0..15
    const int c = (q & 63) * 4;        // col 0..252
    float4 v;
    if (c < 128) v = *(const float4*)(cu_ + (size_t)(row0+r)*128 + c);
    else         v = *(const float4*)(hin + (size_t)(row0+r)*128 + (c-128));
    unsigned short hx, lx, hy, ly, hz, lz, hw, lw;
    split2(v.x, hx, lx); split2(v.y, hy, ly);
    split2(v.z, hz, lz); split2(v.w, hw, lw);
    ushort4v h4; h4[0]=hx; h4[1]=hy; h4[2]=hz; h4[3]=hw;
    ushort4v l4; l4[0]=lx; l4[1]=ly; l4[2]=lz; l4[3]=lw;
    const int byte = (c*2) ^ ((r & 7) << 4);
    *(ushort4v*)(zH + r*512 + byte) = h4;
    *(ushort4v*)(zL + r*512 + byte) = l4;
  }
  __syncthreads();

  const int ln = t & 63, wv = t >> 6;
  const int n0 = wv * 32;
  const int lr = ln & 15, kid = ln >> 4;
  const int sw = (lr & 7) << 4;
  const f32x4 zero = {0.f, 0.f, 0.f, 0.f};

  // ---- u,r GEMMs (K=256) ----
  f32x4 accU[2] = {zero, zero}, accR[2] = {zero, zero};
#pragma unroll
  for (int ks = 0; ks < 8; ++ks) {
    const int kb = ks*64 + kid*16;
    const bf16x8 ah = *(const bf16x8*)(zH + lr*512 + (kb ^ sw));
    const bf16x8 al = *(const bf16x8*)(zL + lr*512 + (kb ^ sw));
#pragma unroll
    for (int nt = 0; nt < 2; ++nt) {
      const int j = n0 + nt*16 + lr;
      const bf16x8 buH = *(const bf16x8*)((const char*)wuh + j*512 + kb);
      const bf16x8 buL = *(const bf16x8*)((const char*)wul + j*512 + kb);
      const bf16x8 brH = *(const bf16x8*)((const char*)wrh + j*512 + kb);
      const bf16x8 brL = *(const bf16x8*)((const char*)wrl + j*512 + kb);
      accU[nt] = MFMA_BF16(ah, buH, accU[nt]);
      accU[nt] = MFMA_BF16(ah, buL, accU[nt]);
      accU[nt] = MFMA_BF16(al, buH, accU[nt]);
      accR[nt] = MFMA_BF16(ah, brH, accR[nt]);
      accR[nt] = MFMA_BF16(ah, brL, accR[nt]);
      accR[nt] = MFMA_BF16(al, brH, accR[nt]);
    }
  }

  // ---- epilogue: u,r -> rh to LDS; keep u,h in regs ----
  float hval[2][4], uval[2][4];
#pragma unroll
  for (int nt = 0; nt < 2; ++nt) {
    const int colg = n0 + nt*16 + lr;
#pragma unroll
    for (int reg = 0; reg < 4; ++reg) {
      const int row16 = kid*4 + reg;
      const int grow = row0 + row16;
      const int nrow = grow & (NN-1);
      const float h_ = hin[(size_t)grow*128 + colg];
      const float uv = 1.f/(1.f + expf(-(bu[nrow] + accU[nt][reg])));
      const float rv = 1.f/(1.f + expf(-(br[nrow] + accR[nt][reg])));
      hval[nt][reg] = h_; uval[nt][reg] = uv;
      unsigned short hs, ls; split2(rv * h_, hs, ls);
      const int byte = (colg*2) ^ ((row16 & 7) << 4);
      *(unsigned short*)(rhH + row16*256 + byte) = hs;
      *(unsigned short*)(rhL + row16*256 + byte) = ls;
    }
  }
  __syncthreads();

  // ---- c GEMM: zc = [conv_u (z cols 0..127) | rh], K=256 ----
  f32x4 accC[2] = {zero, zero};
#pragma unroll
  for (int ks = 0; ks < 8; ++ks) {
    const int kb = ks*64 + kid*16;
    bf16x8 ah, al;
    if (ks < 4) {
      ah = *(const bf16x8*)(zH + lr*512 + (kb ^ sw));
      al = *(const bf16x8*)(zL + lr*512 + (kb ^ sw));
    } else {
      const int kb2 = (ks-4)*64 + kid*16;
      ah = *(const bf16x8*)(rhH + lr*256 + (kb2 ^ sw));
      al = *(const bf16x8*)(rhL + lr*256 + (kb2 ^ sw));
    }
#pragma unroll
    for (int nt = 0; nt < 2; ++nt) {
      const int j = n0 + nt*16 + lr;
      const bf16x8 bH = *(const bf16x8*)((const char*)wch + j*512 + kb);
      const bf16x8 bL = *(const bf16x8*)((const char*)wcl + j*512 + kb);
      accC[nt] = MFMA_BF16(ah, bH, accC[nt]);
      accC[nt] = MFMA_BF16(ah, bL, accC[nt]);
      accC[nt] = MFMA_BF16(al, bH, accC[nt]);
    }
  }

  // ---- epilogue: c -> h'; write f32 h' + bf16 h'; h' split to LDS ----
#pragma unroll
  for (int nt = 0; nt < 2; ++nt) {
    const int colg = n0 + nt*16 + lr;
#pragma unroll
    for (int reg = 0; reg < 4; ++reg) {
      const int row16 = kid*4 + reg;
      const int grow = row0 + row16;
      const int nrow = grow & (NN-1);
      const float cc = tanhf(bc[nrow] + accC[nt][reg]);
      const float uv = uval[nt][reg];
      const float hpv = uv*hval[nt][reg] + (1.f - uv)*cc;
      hp_out[(size_t)grow*128 + colg] = hpv;
      hp_bf[(size_t)grow*128 + colg] = __float2bfloat16(hpv);
      unsigned short hs, ls; split2(hpv, hs, ls);
      const int byte = (colg*2) ^ ((row16 & 7) << 4);
      *(unsigned short*)(hpH  + row16*256 + byte) = hs;
      *(unsigned short*)(hpLo + row16*256 + byte) = ls;
    }
  }
  __syncthreads();

  // ---- t = h' @ R_p (K=128) ----
  f32x4 accT[2] = {zero, zero};
#pragma unroll
  for (int ks = 0; ks < 4; ++ks) {
    const int kb = ks*64 + kid*16;
    const bf16x8 ah = *(const bf16x8*)(hpH  + lr*256 + (kb ^ sw));
    const bf16x8 al = *(const bf16x8*)(hpLo + lr*256 + (kb ^ sw));
#pragma unroll
    for (int nt = 0; nt < 2; ++nt) {
      const int j = n0 + nt*16 + lr;
      const bf16x8 bH = *(const bf16x8*)((const char*)rph + j*256 + kb);
      const bf16x8 bL = *(const bf16x8*)((const char*)rpl + j*256 + kb);
      accT[nt] = MFMA_BF16(ah, bH, accT[nt]);
      accT[nt] = MFMA_BF16(ah, bL, accT[nt]);
      accT[nt] = MFMA_BF16(al, bH, accT[nt]);
    }
  }
#pragma unroll
  for (int nt = 0; nt < 2; ++nt) {
    const int colg = n0 + nt*16 + lr;
#pragma unroll
    for (int reg = 0; reg < 4; ++reg) {
      const int grow = row0 + kid*4 + reg;
      t_bf[(size_t)grow*128 + colg] = __float2bfloat16(accT[nt][reg]);
    }
  }
}

// ---------------------------------------------------------------------------
// k4b: A[b] = t[b] @ hp[b]^T via bf16 MFMA 16x16x32. (unchanged, verified)
// ---------------------------------------------------------------------------
__global__ __launch_bounds__(256) void k4b_dec(
    const __hip_bfloat16* __restrict__ t_bf,
    const __hip_bfloat16* __restrict__ hp_bf,
    float* __restrict__ A)
{
  __shared__ __align__(16) char Alds[128*256];  // 32 KB
  __shared__ __align__(16) char Blds[128*256];  // 32 KB
  const int t = threadIdx.x;
  const int ln = t & 63, wv = t >> 6;
  const int b = blockIdx.z;
  const int i0 = blockIdx.y * 128, j0 = blockIdx.x * 128;

  {
    const int sub = ln >> 4;
    const int cb  = (ln & 15) * 16;
#pragma unroll
    for (int q = 0; q < 8; ++q) {
      const int chunk = wv*8 + q;
      const int row = chunk*4 + sub;
      const int scb = cb ^ ((row & 7) << 4);
      const ushort8 va = *(const ushort8*)
          ((const char*)(t_bf + ((size_t)(b*NN) + i0 + row)*128) + cb);
      *(ushort8*)(Alds + row*256 + scb) = va;
      const ushort8 vb = *(const ushort8*)
          ((const char*)(hp_bf + ((size_t)(b*NN) + j0 + row)*128) + cb);
      *(ushort8*)(Blds + row*256 + scb) = vb;
    }
  }
  __syncthreads();

  const int wr = wv >> 1, wc = wv & 1;
  const int lrow = ln & 15;
  const int kid  = ln >> 4;
  f32x4 acc[4][4];
  const f32x4 zero = {0.f, 0.f, 0.f, 0.f};
#pragma unroll
  for (int m = 0; m < 4; ++m)
#pragma unroll
    for (int n = 0; n < 4; ++n) acc[m][n] = zero;

#pragma unroll
  for (int ks = 0; ks < 4; ++ks) {
    const int kb = ks*64 + kid*16;
    bf16x8 af[4], bfr[4];
#pragma unroll
    for (int m = 0; m < 4; ++m) {
      const int arow = wr*64 + m*16 + lrow;
      af[m] = *(const bf16x8*)(Alds + arow*256 + (kb ^ ((arow & 7) << 4)));
      const int brow = wc*64 + m*16 + lrow;
      bfr[m] = *(const bf16x8*)(Blds + brow*256 + (kb ^ ((brow & 7) << 4)));
    }
#pragma unroll
    for (int m = 0; m < 4; ++m)
#pragma unroll
      for (int n = 0; n < 4; ++n)
        acc[m][n] = MFMA_BF16(af[m], bfr[n], acc[m][n]);
  }

#pragma unroll
  for (int m = 0; m < 4; ++m) {
    const int grow = i0 + wr*64 + m*16 + (ln >> 4)*4;
#pragma unroll
    for (int n = 0; n < 4; ++n) {
      const int gcol = j0 + wc*64 + n*16 + (ln & 15);
      float* Ap = A + ((size_t)b*NN + grow)*NN + gcol;
#pragma unroll
      for (int r = 0; r < 4; ++r)
        Ap[(size_t)r*NN] = acc[m][n][r];
    }
  }
}

// ---------------------------------------------------------------------------
extern "C" void kernel_launch(void* const* d_in, const int* in_sizes, int n_in,
                              void* d_out, int out_size, void* d_ws, size_t ws_size,
                              hipStream_t stream)
{
  const float* x    = (const float*)d_in[0];
  const float* a    = (const float*)d_in[1];
  const float* h    = (const float*)d_in[2];
  const float* kern = (const float*)d_in[3];
  const float* as_  = (const float*)d_in[4];
  const float* an_  = (const float*)d_in[5];
  const float* bias = (const float*)d_in[6];
  const float* bu   = (const float*)d_in[7];
  const float* br   = (const float*)d_in[8];
  const float* bc   = (const float*)d_in[9];
  const float* Wu   = (const float*)d_in[10];
  const float* Wr   = (const float*)d_in[11];
  const float* Wc   = (const float*)d_in[12];
  const float* Rp   = (const float*)d_in[13];
  (void)in_sizes; (void)n_in; (void)out_size; (void)ws_size;

  float* ws = (float*)d_ws;
  float* xp = ws + XP_OFF;
  float* es = ws + ES_OFF;
  float* en = ws + EN_OFF;
  float* cu = ws + CU_OFF;
  __hip_bfloat16* t_bf  = (__hip_bfloat16*)(ws + TBF_OFF);
  __hip_bfloat16* hp_bf = (__hip_bfloat16*)(ws + HPBF_OFF);
  unsigned short* wuh = (unsigned short*)(ws + WUH_OFF);
  unsigned short* wul = (unsigned short*)(ws + WUL_OFF);
  unsigned short* wrh = (unsigned short*)(ws + WRH_OFF);
  unsigned short* wrl = (unsigned short*)(ws + WRL_OFF);
  unsigned short* wch = (unsigned short*)(ws + WCH_OFF);
  unsigned short* wcl = (unsigned short*)(ws + WCL_OFF);
  unsigned short* rph = (unsigned short*)(ws + RPH_OFF);
  unsigned short* rpl = (unsigned short*)(ws + RPL_OFF);

  float* A  = (float*)d_out;
  float* hp = (float*)d_out + A_ELEMS;

  hipLaunchKernelGGL(k0_prep, dim3(448), dim3(256), 0, stream,
                     Wu, Wr, Wc, Rp, wuh, wul, wrh, wrl, wch, wcl, rph, rpl);
  hipLaunchKernelGGL(k1_xp,   dim3(ROWS_TOT/8), dim3(256), 0, stream,
                     x, kern, as_, an_, xp, es, en);
  hipLaunchKernelGGL(k2_attn, dim3(ROWS_TOT/4), dim3(256), 0, stream,
                     a, xp, es, en, bias, cu);
  hipLaunchKernelGGL(k3_mfma, dim3(ROWS_TOT/16), dim3(256), 0, stream,
                     cu, h, bu, br, bc, wuh, wul, wrh, wrl, wch, wcl, rph, rpl,
                     hp, hp_bf, t_bf);
  hipLaunchKernelGGL(k4b_dec, dim3(NN/128, NN/128, NB), dim3(256), 0, stream,
                     t_bf, hp_bf, A);
}

// Round 11
// 143.501 us; speedup vs baseline: 1.6811x; 1.0682x over previous
//
#include <hip/hip_runtime.h>
#include <hip/hip_bf16.h>
#include <math.h>

// Problem dims
#define NB 2
#define NN 2048
#define FD 64
#define NH 4
#define HIDD 128
#define ROWS_TOT (NB*NN)   // 4096

// ws layout (float offsets). Total 1,720,320 floats = 6.88 MB.
#define XP_OFF   0
#define ES_OFF   524288
#define EN_OFF   540672
#define CU_OFF   557056
#define TBF_OFF  1081344   // bf16 t  [4096][128]
#define HPBF_OFF 1343488   // bf16 h' [4096][128]
// prep: fragment-ordered bf16 hi/lo weights: [jt][ks][lane] bf16x8
#define WUH_OFF  1605632   // 32768 bf16 = 16384 floats each
#define WUL_OFF  1622016
#define WRH_OFF  1638400
#define WRL_OFF  1654784
#define WCH_OFF  1671168
#define WCL_OFF  1687552
#define RPH_OFF  1703936   // 16384 bf16 = 8192 floats each
#define RPL_OFF  1712128

#define A_ELEMS (NB*NN*NN)

typedef __attribute__((ext_vector_type(8))) short bf16x8;
typedef __attribute__((ext_vector_type(8))) unsigned short ushort8;
typedef __attribute__((ext_vector_type(4))) unsigned short ushort4v;
typedef __attribute__((ext_vector_type(4))) float f32x4;

#define MFMA_BF16(a,b,c) __builtin_amdgcn_mfma_f32_16x16x32_bf16((a),(b),(c),0,0,0)

static __device__ inline unsigned short f2bf(float x) {
  __hip_bfloat16 b = __float2bfloat16(x);
  unsigned short u; __builtin_memcpy(&u, &b, 2); return u;
}
static __device__ inline float bf2f(unsigned short u) {
  __hip_bfloat16 b; __builtin_memcpy(&b, &u, 2); return __bfloat162float(b);
}
static __device__ inline void split2(float x, unsigned short& hi, unsigned short& lo) {
  hi = f2bf(x);
  lo = f2bf(x - bf2f(hi));
}

// ---------------------------------------------------------------------------
// k0: prep — hi/lo bf16 split of Wu/Wr/Wc/Rp into MFMA B-fragment order:
// frag element loc = ((jt*KS + ks)*64 + ln)*8 + e holds
//   W[k = ks*32 + (ln>>4)*8 + e][j = jt*16 + (ln&15)]
// so a wave's B-load for tile (jt,ks) is 64 lanes x 16 B CONTIGUOUS.
// ---------------------------------------------------------------------------
__global__ __launch_bounds__(256) void k0_prep(
    const float* __restrict__ Wu, const float* __restrict__ Wr,
    const float* __restrict__ Wc, const float* __restrict__ Rp,
    unsigned short* __restrict__ wuh, unsigned short* __restrict__ wul,
    unsigned short* __restrict__ wrh, unsigned short* __restrict__ wrl,
    unsigned short* __restrict__ wch, unsigned short* __restrict__ wcl,
    unsigned short* __restrict__ rph, unsigned short* __restrict__ rpl)
{
  const int gid = blockIdx.x*256 + threadIdx.x;
  if (gid < 98304) {             // Wu/Wr/Wc: K=256 -> KS=8
    const int which = gid >> 15;
    const int loc = gid & 32767;
    const int e  = loc & 7;
    const int ln = (loc >> 3) & 63;
    const int ks = (loc >> 9) & 7;
    const int jt = loc >> 12;
    const int j = jt*16 + (ln & 15);
    const int k = ks*32 + ((ln >> 4) << 3) + e;
    const float* W = which == 0 ? Wu : (which == 1 ? Wr : Wc);
    unsigned short* oh = which == 0 ? wuh : (which == 1 ? wrh : wch);
    unsigned short* ol = which == 0 ? wul : (which == 1 ? wrl : wcl);
    unsigned short h, l; split2(W[k*128 + j], h, l);
    oh[loc] = h; ol[loc] = l;
  } else if (gid < 114688) {     // Rp: K=128 -> KS=4
    const int loc = gid - 98304;
    const int e  = loc & 7;
    const int ln = (loc >> 3) & 63;
    const int ks = (loc >> 9) & 3;
    const int jt = loc >> 11;
    const int j = jt*16 + (ln & 15);
    const int k = ks*32 + ((ln >> 4) << 3) + e;
    unsigned short h, l; split2(Rp[k*128 + j], h, l);
    rph[loc] = h; rpl[loc] = l;
  }
}

// ---------------------------------------------------------------------------
// k1: xp = x @ kernel, plus per-head scores es/en. (unchanged from r9)
// ---------------------------------------------------------------------------
__global__ __launch_bounds__(256) void k1_xp(
    const float* __restrict__ x, const float* __restrict__ kern,
    const float* __restrict__ as_, const float* __restrict__ an_,
    float* __restrict__ xp, float* __restrict__ es, float* __restrict__ en)
{
  __shared__ float xr[8][FD];
  const int t = threadIdx.x;
  const int row0 = blockIdx.x * 8;
  for (int idx = t; idx < 8*FD; idx += 256)
    xr[idx >> 6][idx & 63] = x[(size_t)row0*FD + idx];
  __syncthreads();
  const int c4 = (t & 31) * 4;
  const int rq = t >> 5;
  const float4 asv = *(const float4*)(as_ + c4);
  const float4 anv = *(const float4*)(an_ + c4);
  float4 acc = make_float4(0.f, 0.f, 0.f, 0.f);
  for (int f = 0; f < FD; ++f) {
    const float4 kv = *(const float4*)(kern + f*128 + c4);
    const float xv = xr[rq][f];
    acc.x = fmaf(xv, kv.x, acc.x);
    acc.y = fmaf(xv, kv.y, acc.y);
    acc.z = fmaf(xv, kv.z, acc.z);
    acc.w = fmaf(xv, kv.w, acc.w);
  }
  const int grow = row0 + rq;
  *(float4*)(xp + (size_t)grow*128 + c4) = acc;
  float s  = acc.x*asv.x + acc.y*asv.y + acc.z*asv.z + acc.w*asv.w;
  float n_ = acc.x*anv.x + acc.y*anv.y + acc.z*anv.z + acc.w*anv.w;
#pragma unroll
  for (int mk = 4; mk >= 1; mk >>= 1) {
    s  += __shfl_xor(s,  mk, 64);
    n_ += __shfl_xor(n_, mk, 64);
  }
  if ((t & 7) == 0) {
    const int h = (t & 31) >> 3;
    es[grow*NH + h] = s; en[grow*NH + h] = n_;
  }
}

// ---------------------------------------------------------------------------
// k2: sparse masked softmax + aggregation, wave-per-row. (unchanged from r4)
// ---------------------------------------------------------------------------
__global__ __launch_bounds__(256) void k2_attn(
    const float* __restrict__ a, const float* __restrict__ xp,
    const float* __restrict__ es, const float* __restrict__ en,
    const float* __restrict__ bias, float* __restrict__ cu)
{
  __shared__ unsigned short sidx[4][NN];   // 16 KB
  __shared__ float swl[4][64][NH];         // 4 KB
  const int t = threadIdx.x;
  const int ln = t & 63, wv = t >> 6;
  const int row = blockIdx.x * 4 + wv;
  const int b = row >> 11;
  const float4 esi = *(const float4*)(es + (size_t)row*NH);

  int deg = 0;
  const float4* arow4 = (const float4*)(a + (size_t)row*NN);
#pragma unroll
  for (int cch = 0; cch < 8; ++cch) {
    const float4 v = arow4[cch*64 + ln];
    const int j0 = cch*256 + ln*4;
    const float vv[4] = {v.x, v.y, v.z, v.w};
#pragma unroll
    for (int q = 0; q < 4; ++q) {
      const unsigned long long m = __ballot(vv[q] > 0.5f);
      if (vv[q] > 0.5f) {
        const int pos = deg + (int)__popcll(m & ((1ull << ln) - 1ull));
        sidx[wv][pos] = (unsigned short)(j0 + q);
      }
      deg += (int)__popcll(m);
    }
  }

  const int col0 = ln, col1 = ln + 64;
  const int h0 = ln >> 5;
  float m0=-1e30f, m1=-1e30f, m2=-1e30f, m3=-1e30f;
  float s0=0.f, s1=0.f, s2=0.f, s3=0.f;
  float acc0=0.f, acc1=0.f;
  for (int base = 0; base < deg; base += 64) {
    const int rem = min(64, deg - base);
    float t0=-1e30f, t1=-1e30f, t2=-1e30f, t3=-1e30f;
    if (ln < rem) {
      const int j = sidx[wv][base + ln];
      const float4 e4 = *(const float4*)(en + (size_t)(b*NN + j)*NH);
      t0 = esi.x + e4.x; t0 = t0 > 0.f ? t0 : 0.2f*t0;
      t1 = esi.y + e4.y; t1 = t1 > 0.f ? t1 : 0.2f*t1;
      t2 = esi.z + e4.z; t2 = t2 > 0.f ? t2 : 0.2f*t2;
      t3 = esi.w + e4.w; t3 = t3 > 0.f ? t3 : 0.2f*t3;
    }
    float c0=t0, c1=t1, c2=t2, c3=t3;
#pragma unroll
    for (int mk = 32; mk >= 1; mk >>= 1) {
      c0 = fmaxf(c0, __shfl_xor(c0, mk));
      c1 = fmaxf(c1, __shfl_xor(c1, mk));
      c2 = fmaxf(c2, __shfl_xor(c2, mk));
      c3 = fmaxf(c3, __shfl_xor(c3, mk));
    }
    const float nm0 = fmaxf(m0,c0), nm1 = fmaxf(m1,c1);
    const float nm2 = fmaxf(m2,c2), nm3 = fmaxf(m3,c3);
    const float r0 = expf(m0-nm0), r1 = expf(m1-nm1);
    const float r2 = expf(m2-nm2), r3 = expf(m3-nm3);
    s0 *= r0; s1 *= r1; s2 *= r2; s3 *= r3;
    float w0=0.f, w1=0.f, w2=0.f, w3=0.f;
    if (ln < rem) {
      w0 = expf(t0-nm0); w1 = expf(t1-nm1);
      w2 = expf(t2-nm2); w3 = expf(t3-nm3);
    }
    float u0=w0, u1=w1, u2=w2, u3=w3;
#pragma unroll
    for (int mk = 32; mk >= 1; mk >>= 1) {
      u0 += __shfl_xor(u0, mk);
      u1 += __shfl_xor(u1, mk);
      u2 += __shfl_xor(u2, mk);
      u3 += __shfl_xor(u3, mk);
    }
    s0 += u0; s1 += u1; s2 += u2; s3 += u3;
    acc0 *= (h0 ? r1 : r0);
    acc1 *= (h0 ? r3 : r2);
    swl[wv][ln][0] = w0; swl[wv][ln][1] = w1;
    swl[wv][ln][2] = w2; swl[wv][ln][3] = w3;
#pragma unroll 4
    for (int k = 0; k < rem; ++k) {
      const int j = sidx[wv][base + k];
      const float* xr = xp + (size_t)(b*NN + j)*128;
      acc0 = fmaf(swl[wv][k][h0],     xr[col0], acc0);
      acc1 = fmaf(swl[wv][k][2 + h0], xr[col1], acc1);
    }
    m0=nm0; m1=nm1; m2=nm2; m3=nm3;
  }
  const float den0 = h0 ? s1 : s0;
  const float den1 = h0 ? s3 : s2;
  cu[(size_t)row*128 + col0] = acc0/den0 + bias[col0];
  cu[(size_t)row*128 + col1] = acc1/den1 + bias[col1];
}

// ---------------------------------------------------------------------------
// k3: fused GRU gates + t = h'@R_p via 3-term split-bf16 MFMA.
// 256 blocks x 512 thr (8 waves, 2/SIMD); wave wv owns 16 cols (jt = wv).
// B-frags are single COALESCED 1KB wave-loads from the fragment-ordered
// buffers (k0). LDS swizzle unchanged (verified).
// ---------------------------------------------------------------------------
__global__ __launch_bounds__(512) void k3_mfma(
    const float* __restrict__ cu_, const float* __restrict__ hin,
    const float* __restrict__ bu, const float* __restrict__ br,
    const float* __restrict__ bc,
    const unsigned short* __restrict__ wuh, const unsigned short* __restrict__ wul,
    const unsigned short* __restrict__ wrh, const unsigned short* __restrict__ wrl,
    const unsigned short* __restrict__ wch, const unsigned short* __restrict__ wcl,
    const unsigned short* __restrict__ rph, const unsigned short* __restrict__ rpl,
    float* __restrict__ hp_out,
    __hip_bfloat16* __restrict__ hp_bf, __hip_bfloat16* __restrict__ t_bf)
{
  __shared__ __align__(16) char zH[16*512];   // z hi  [16][256] bf16
  __shared__ __align__(16) char zL[16*512];   // z lo
  __shared__ __align__(16) char rhH[16*256];  // r*h hi [16][128] bf16
  __shared__ __align__(16) char rhL[16*256];
  __shared__ __align__(16) char hpH[16*256];  // h' hi
  __shared__ __align__(16) char hpLo[16*256];
  const int t = threadIdx.x;
  const int row0 = blockIdx.x * 16;

  // ---- stage z = [cu | h] as split bf16, swizzled ----
#pragma unroll
  for (int i = 0; i < 2; ++i) {
    const int q = t + 512*i;           // float4 id 0..1023
    const int r = q >> 6;              // row 0..15
    const int c = (q & 63) * 4;        // col 0..252
    float4 v;
    if (c < 128) v = *(const float4*)(cu_ + (size_t)(row0+r)*128 + c);
    else         v = *(const float4*)(hin + (size_t)(row0+r)*128 + (c-128));
    unsigned short hx, lx, hy, ly, hz, lz, hw, lw;
    split2(v.x, hx, lx); split2(v.y, hy, ly);
    split2(v.z, hz, lz); split2(v.w, hw, lw);
    ushort4v h4; h4[0]=hx; h4[1]=hy; h4[2]=hz; h4[3]=hw;
    ushort4v l4; l4[0]=lx; l4[1]=ly; l4[2]=lz; l4[3]=lw;
    const int byte = (c*2) ^ ((r & 7) << 4);
    *(ushort4v*)(zH + r*512 + byte) = h4;
    *(ushort4v*)(zL + r*512 + byte) = l4;
  }
  __syncthreads();

  const int ln = t & 63, wv = t >> 6;       // wv 0..7 = jt
  const int lr = ln & 15, kid = ln >> 4;
  const int sw = (lr & 7) << 4;
  const int colg = wv*16 + lr;
  const f32x4 zero = {0.f, 0.f, 0.f, 0.f};
  const bf16x8* wuhF = (const bf16x8*)wuh;
  const bf16x8* wulF = (const bf16x8*)wul;
  const bf16x8* wrhF = (const bf16x8*)wrh;
  const bf16x8* wrlF = (const bf16x8*)wrl;
  const bf16x8* wchF = (const bf16x8*)wch;
  const bf16x8* wclF = (const bf16x8*)wcl;
  const bf16x8* rphF = (const bf16x8*)rph;
  const bf16x8* rplF = (const bf16x8*)rpl;

  // ---- u,r GEMMs (K=256) ----
  f32x4 accU = zero, accR = zero;
#pragma unroll
  for (int ks = 0; ks < 8; ++ks) {
    const int kb = ks*64 + kid*16;
    const bf16x8 ah = *(const bf16x8*)(zH + lr*512 + (kb ^ sw));
    const bf16x8 al = *(const bf16x8*)(zL + lr*512 + (kb ^ sw));
    const int fb = (wv*8 + ks)*64 + ln;
    const bf16x8 buH = wuhF[fb];
    const bf16x8 buL = wulF[fb];
    const bf16x8 brH = wrhF[fb];
    const bf16x8 brL = wrlF[fb];
    accU = MFMA_BF16(ah, buH, accU);
    accU = MFMA_BF16(ah, buL, accU);
    accU = MFMA_BF16(al, buH, accU);
    accR = MFMA_BF16(ah, brH, accR);
    accR = MFMA_BF16(ah, brL, accR);
    accR = MFMA_BF16(al, brH, accR);
  }

  // ---- epilogue: u,r -> rh to LDS; keep u,h in regs ----
  float hval[4], uval[4];
#pragma unroll
  for (int reg = 0; reg < 4; ++reg) {
    const int row16 = kid*4 + reg;
    const int grow = row0 + row16;
    const int nrow = grow & (NN-1);
    const float h_ = hin[(size_t)grow*128 + colg];
    const float uv = 1.f/(1.f + expf(-(bu[nrow] + accU[reg])));
    const float rv = 1.f/(1.f + expf(-(br[nrow] + accR[reg])));
    hval[reg] = h_; uval[reg] = uv;
    unsigned short hs, ls; split2(rv * h_, hs, ls);
    const int byte = (colg*2) ^ ((row16 & 7) << 4);
    *(unsigned short*)(rhH + row16*256 + byte) = hs;
    *(unsigned short*)(rhL + row16*256 + byte) = ls;
  }
  __syncthreads();

  // ---- c GEMM: zc = [conv_u (z cols 0..127) | rh], K=256 ----
  f32x4 accC = zero;
#pragma unroll
  for (int ks = 0; ks < 8; ++ks) {
    const int kb = ks*64 + kid*16;
    bf16x8 ah, al;
    if (ks < 4) {
      ah = *(const bf16x8*)(zH + lr*512 + (kb ^ sw));
      al = *(const bf16x8*)(zL + lr*512 + (kb ^ sw));
    } else {
      const int kb2 = (ks-4)*64 + kid*16;
      ah = *(const bf16x8*)(rhH + lr*256 + (kb2 ^ sw));
      al = *(const bf16x8*)(rhL + lr*256 + (kb2 ^ sw));
    }
    const int fb = (wv*8 + ks)*64 + ln;
    const bf16x8 bH = wchF[fb];
    const bf16x8 bL = wclF[fb];
    accC = MFMA_BF16(ah, bH, accC);
    accC = MFMA_BF16(ah, bL, accC);
    accC = MFMA_BF16(al, bH, accC);
  }

  // ---- epilogue: c -> h'; write f32 h' + bf16 h'; h' split to LDS ----
#pragma unroll
  for (int reg = 0; reg < 4; ++reg) {
    const int row16 = kid*4 + reg;
    const int grow = row0 + row16;
    const int nrow = grow & (NN-1);
    const float cc = tanhf(bc[nrow] + accC[reg]);
    const float uv = uval[reg];
    const float hpv = uv*hval[reg] + (1.f - uv)*cc;
    hp_out[(size_t)grow*128 + colg] = hpv;
    hp_bf[(size_t)grow*128 + colg] = __float2bfloat16(hpv);
    unsigned short hs, ls; split2(hpv, hs, ls);
    const int byte = (colg*2) ^ ((row16 & 7) << 4);
    *(unsigned short*)(hpH  + row16*256 + byte) = hs;
    *(unsigned short*)(hpLo + row16*256 + byte) = ls;
  }
  __syncthreads();

  // ---- t = h' @ R_p (K=128) ----
  f32x4 accT = zero;
#pragma unroll
  for (int ks = 0; ks < 4; ++ks) {
    const int kb = ks*64 + kid*16;
    const bf16x8 ah = *(const bf16x8*)(hpH  + lr*256 + (kb ^ sw));
    const bf16x8 al = *(const bf16x8*)(hpLo + lr*256 + (kb ^ sw));
    const int fb = (wv*4 + ks)*64 + ln;
    const bf16x8 bH = rphF[fb];
    const bf16x8 bL = rplF[fb];
    accT = MFMA_BF16(ah, bH, accT);
    accT = MFMA_BF16(ah, bL, accT);
    accT = MFMA_BF16(al, bH, accT);
  }
#pragma unroll
  for (int reg = 0; reg < 4; ++reg) {
    const int grow = row0 + kid*4 + reg;
    t_bf[(size_t)grow*128 + colg] = __float2bfloat16(accT[reg]);
  }
}

// ---------------------------------------------------------------------------
// k4b: A[b] = t[b] @ hp[b]^T via bf16 MFMA. Accumulator transposed through
// LDS (pad 132) so the A-write is 512B-contiguous float4 stores instead of
// 4B/lane stride-NN scatter.
// ---------------------------------------------------------------------------
__global__ __launch_bounds__(256) void k4b_dec(
    const __hip_bfloat16* __restrict__ t_bf,
    const __hip_bfloat16* __restrict__ hp_bf,
    float* __restrict__ A)
{
  __shared__ __align__(16) char smem[128*132*4];  // 67.5 KB
  char* Alds = smem;             // 32 KB bf16 staging (swizzled)
  char* Blds = smem + 32768;     // 32 KB
  float* Cst = (float*)smem;     // [128][132] f32 reuse after MFMA
  const int t = threadIdx.x;
  const int ln = t & 63, wv = t >> 6;
  const int b = blockIdx.z;
  const int i0 = blockIdx.y * 128, j0 = blockIdx.x * 128;

  {
    const int sub = ln >> 4;
    const int cb  = (ln & 15) * 16;
#pragma unroll
    for (int q = 0; q < 8; ++q) {
      const int chunk = wv*8 + q;
      const int row = chunk*4 + sub;
      const int scb = cb ^ ((row & 7) << 4);
      const ushort8 va = *(const ushort8*)
          ((const char*)(t_bf + ((size_t)(b*NN) + i0 + row)*128) + cb);
      *(ushort8*)(Alds + row*256 + scb) = va;
      const ushort8 vb = *(const ushort8*)
          ((const char*)(hp_bf + ((size_t)(b*NN) + j0 + row)*128) + cb);
      *(ushort8*)(Blds + row*256 + scb) = vb;
    }
  }
  __syncthreads();

  const int wr = wv >> 1, wc = wv & 1;
  const int lrow = ln & 15;
  const int kid  = ln >> 4;
  f32x4 acc[4][4];
  const f32x4 zero = {0.f, 0.f, 0.f, 0.f};
#pragma unroll
  for (int m = 0; m < 4; ++m)
#pragma unroll
    for (int n = 0; n < 4; ++n) acc[m][n] = zero;

#pragma unroll
  for (int ks = 0; ks < 4; ++ks) {
    const int kb = ks*64 + kid*16;
    bf16x8 af[4], bfr[4];
#pragma unroll
    for (int m = 0; m < 4; ++m) {
      const int arow = wr*64 + m*16 + lrow;
      af[m] = *(const bf16x8*)(Alds + arow*256 + (kb ^ ((arow & 7) << 4)));
      const int brow = wc*64 + m*16 + lrow;
      bfr[m] = *(const bf16x8*)(Blds + brow*256 + (kb ^ ((brow & 7) << 4)));
    }
#pragma unroll
    for (int m = 0; m < 4; ++m)
#pragma unroll
      for (int n = 0; n < 4; ++n)
        acc[m][n] = MFMA_BF16(af[m], bfr[n], acc[m][n]);
  }
  __syncthreads();   // all MFMA LDS reads done before Cst overwrite

  // acc -> Cst (pad 132: row-stride shifts banks, conflicts <= 2-way)
#pragma unroll
  for (int m = 0; m < 4; ++m) {
    const int crow = wr*64 + m*16 + kid*4;
#pragma unroll
    for (int n = 0; n < 4; ++n) {
      const int ccol = wc*64 + n*16 + lrow;
#pragma unroll
      for (int r = 0; r < 4; ++r)
        Cst[(crow + r)*132 + ccol] = acc[m][n][r];
    }
  }
  __syncthreads();

  // coalesced writeout: 512B-contiguous rows, float4 per lane
#pragma unroll
  for (int p = 0; p < 16; ++p) {
    const int row = p*8 + (t >> 5);
    const int c4  = (t & 31) * 4;
    const float4 v = *(const float4*)&Cst[row*132 + c4];
    *(float4*)(A + ((size_t)b*NN + i0 + row)*NN + j0 + c4) = v;
  }
}

// ---------------------------------------------------------------------------
extern "C" void kernel_launch(void* const* d_in, const int* in_sizes, int n_in,
                              void* d_out, int out_size, void* d_ws, size_t ws_size,
                              hipStream_t stream)
{
  const float* x    = (const float*)d_in[0];
  const float* a    = (const float*)d_in[1];
  const float* h    = (const float*)d_in[2];
  const float* kern = (const float*)d_in[3];
  const float* as_  = (const float*)d_in[4];
  const float* an_  = (const float*)d_in[5];
  const float* bias = (const float*)d_in[6];
  const float* bu   = (const float*)d_in[7];
  const float* br   = (const float*)d_in[8];
  const float* bc   = (const float*)d_in[9];
  const float* Wu   = (const float*)d_in[10];
  const float* Wr   = (const float*)d_in[11];
  const float* Wc   = (const float*)d_in[12];
  const float* Rp   = (const float*)d_in[13];
  (void)in_sizes; (void)n_in; (void)out_size; (void)ws_size;

  float* ws = (float*)d_ws;
  float* xp = ws + XP_OFF;
  float* es = ws + ES_OFF;
  float* en = ws + EN_OFF;
  float* cu = ws + CU_OFF;
  __hip_bfloat16* t_bf  = (__hip_bfloat16*)(ws + TBF_OFF);
  __hip_bfloat16* hp_bf = (__hip_bfloat16*)(ws + HPBF_OFF);
  unsigned short* wuh = (unsigned short*)(ws + WUH_OFF);
  unsigned short* wul = (unsigned short*)(ws + WUL_OFF);
  unsigned short* wrh = (unsigned short*)(ws + WRH_OFF);
  unsigned short* wrl = (unsigned short*)(ws + WRL_OFF);
  unsigned short* wch = (unsigned short*)(ws + WCH_OFF);
  unsigned short* wcl = (unsigned short*)(ws + WCL_OFF);
  unsigned short* rph = (unsigned short*)(ws + RPH_OFF);
  unsigned short* rpl = (unsigned short*)(ws + RPL_OFF);

  float* A  = (float*)d_out;
  float* hp = (float*)d_out + A_ELEMS;

  hipLaunchKernelGGL(k0_prep, dim3(448), dim3(256), 0, stream,
                     Wu, Wr, Wc, Rp, wuh, wul, wrh, wrl, wch, wcl, rph, rpl);
  hipLaunchKernelGGL(k1_xp,   dim3(ROWS_TOT/8), dim3(256), 0, stream,
                     x, kern, as_, an_, xp, es, en);
  hipLaunchKernelGGL(k2_attn, dim3(ROWS_TOT/4), dim3(256), 0, stream,
                     a, xp, es, en, bias, cu);
  hipLaunchKernelGGL(k3_mfma, dim3(ROWS_TOT/16), dim3(512), 0, stream,
                     cu, h, bu, br, bc, wuh, wul, wrh, wrl, wch, wcl, rph, rpl,
                     hp, hp_bf, t_bf);
  hipLaunchKernelGGL(k4b_dec, dim3(NN/128, NN/128, NB), dim3(256), 0, stream,
                     t_bf, hp_bf, A);
}

// Round 12
// 142.967 us; speedup vs baseline: 1.6874x; 1.0037x over previous
//
#include <hip/hip_runtime.h>
#include <hip/hip_bf16.h>
#include <math.h>

// Problem dims
#define NB 2
#define NN 2048
#define FD 64
#define NH 4
#define HIDD 128
#define ROWS_TOT (NB*NN)   // 4096

// ws layout (float offsets). Total 1,720,320 floats = 6.88 MB.
#define XP_OFF   0
#define ES_OFF   524288
#define EN_OFF   540672
#define CU_OFF   557056
#define TBF_OFF  1081344   // bf16 t  [4096][128]
#define HPBF_OFF 1343488   // bf16 h' [4096][128]
// prep: fragment-ordered bf16 hi/lo weights: [jt][ks][lane] bf16x8
#define WUH_OFF  1605632
#define WUL_OFF  1622016
#define WRH_OFF  1638400
#define WRL_OFF  1654784
#define WCH_OFF  1671168
#define WCL_OFF  1687552
#define RPH_OFF  1703936
#define RPL_OFF  1712128

#define A_ELEMS (NB*NN*NN)

typedef __attribute__((ext_vector_type(8))) short bf16x8;
typedef __attribute__((ext_vector_type(8))) unsigned short ushort8;
typedef __attribute__((ext_vector_type(4))) unsigned short ushort4v;
typedef __attribute__((ext_vector_type(4))) float f32x4;

#define MFMA_BF16(a,b,c) __builtin_amdgcn_mfma_f32_16x16x32_bf16((a),(b),(c),0,0,0)

static __device__ inline unsigned short f2bf(float x) {
  __hip_bfloat16 b = __float2bfloat16(x);
  unsigned short u; __builtin_memcpy(&u, &b, 2); return u;
}
static __device__ inline float bf2f(unsigned short u) {
  __hip_bfloat16 b; __builtin_memcpy(&b, &u, 2); return __bfloat162float(b);
}
static __device__ inline void split2(float x, unsigned short& hi, unsigned short& lo) {
  hi = f2bf(x);
  lo = f2bf(x - bf2f(hi));
}

// ---------------------------------------------------------------------------
// k01: fused prep (blocks 0..447) + xp/es/en (blocks 448..959).
// prep: hi/lo bf16 split of Wu/Wr/Wc/Rp into MFMA B-fragment order
//   loc = ((jt*KS + ks)*64 + ln)*8 + e  holds  W[ks*32+(ln>>4)*8+e][jt*16+(ln&15)]
// so a wave's B-load for tile (jt,ks) is 64 lanes x 16 B CONTIGUOUS.
// ---------------------------------------------------------------------------
__global__ __launch_bounds__(256) void k01_prep_xp(
    const float* __restrict__ Wu, const float* __restrict__ Wr,
    const float* __restrict__ Wc, const float* __restrict__ Rp,
    unsigned short* __restrict__ wuh, unsigned short* __restrict__ wul,
    unsigned short* __restrict__ wrh, unsigned short* __restrict__ wrl,
    unsigned short* __restrict__ wch, unsigned short* __restrict__ wcl,
    unsigned short* __restrict__ rph, unsigned short* __restrict__ rpl,
    const float* __restrict__ x, const float* __restrict__ kern,
    const float* __restrict__ as_, const float* __restrict__ an_,
    float* __restrict__ xp, float* __restrict__ es, float* __restrict__ en)
{
  __shared__ float xr[8][FD];
  const int t = threadIdx.x;
  if (blockIdx.x < 448) {
    const int gid = blockIdx.x*256 + t;
    if (gid < 98304) {             // Wu/Wr/Wc: K=256 -> KS=8
      const int which = gid >> 15;
      const int loc = gid & 32767;
      const int e  = loc & 7;
      const int ln = (loc >> 3) & 63;
      const int ks = (loc >> 9) & 7;
      const int jt = loc >> 12;
      const int j = jt*16 + (ln & 15);
      const int k = ks*32 + ((ln >> 4) << 3) + e;
      const float* W = which == 0 ? Wu : (which == 1 ? Wr : Wc);
      unsigned short* oh = which == 0 ? wuh : (which == 1 ? wrh : wch);
      unsigned short* ol = which == 0 ? wul : (which == 1 ? wrl : wcl);
      unsigned short h, l; split2(W[k*128 + j], h, l);
      oh[loc] = h; ol[loc] = l;
    } else if (gid < 114688) {     // Rp: K=128 -> KS=4
      const int loc = gid - 98304;
      const int e  = loc & 7;
      const int ln = (loc >> 3) & 63;
      const int ks = (loc >> 9) & 3;
      const int jt = loc >> 11;
      const int j = jt*16 + (ln & 15);
      const int k = ks*32 + ((ln >> 4) << 3) + e;
      unsigned short h, l; split2(Rp[k*128 + j], h, l);
      rph[loc] = h; rpl[loc] = l;
    }
    return;
  }
  // ---- k1 part ----
  const int row0 = (blockIdx.x - 448) * 8;
  for (int idx = t; idx < 8*FD; idx += 256)
    xr[idx >> 6][idx & 63] = x[(size_t)row0*FD + idx];
  __syncthreads();
  const int c4 = (t & 31) * 4;
  const int rq = t >> 5;
  const float4 asv = *(const float4*)(as_ + c4);
  const float4 anv = *(const float4*)(an_ + c4);
  float4 acc = make_float4(0.f, 0.f, 0.f, 0.f);
#pragma unroll 8
  for (int f = 0; f < FD; ++f) {
    const float4 kv = *(const float4*)(kern + f*128 + c4);
    const float xv = xr[rq][f];
    acc.x = fmaf(xv, kv.x, acc.x);
    acc.y = fmaf(xv, kv.y, acc.y);
    acc.z = fmaf(xv, kv.z, acc.z);
    acc.w = fmaf(xv, kv.w, acc.w);
  }
  const int grow = row0 + rq;
  *(float4*)(xp + (size_t)grow*128 + c4) = acc;
  float s  = acc.x*asv.x + acc.y*asv.y + acc.z*asv.z + acc.w*asv.w;
  float n_ = acc.x*anv.x + acc.y*anv.y + acc.z*anv.z + acc.w*anv.w;
#pragma unroll
  for (int mk = 4; mk >= 1; mk >>= 1) {
    s  += __shfl_xor(s,  mk, 64);
    n_ += __shfl_xor(n_, mk, 64);
  }
  if ((t & 7) == 0) {
    const int h = (t & 31) >> 3;
    es[grow*NH + h] = s; en[grow*NH + h] = n_;
  }
}

// ---------------------------------------------------------------------------
// k2: sparse masked softmax + aggregation, wave-per-row. (unchanged, verified)
// ---------------------------------------------------------------------------
__global__ __launch_bounds__(256) void k2_attn(
    const float* __restrict__ a, const float* __restrict__ xp,
    const float* __restrict__ es, const float* __restrict__ en,
    const float* __restrict__ bias, float* __restrict__ cu)
{
  __shared__ unsigned short sidx[4][NN];   // 16 KB
  __shared__ float swl[4][64][NH];         // 4 KB
  const int t = threadIdx.x;
  const int ln = t & 63, wv = t >> 6;
  const int row = blockIdx.x * 4 + wv;
  const int b = row >> 11;
  const float4 esi = *(const float4*)(es + (size_t)row*NH);

  int deg = 0;
  const float4* arow4 = (const float4*)(a + (size_t)row*NN);
#pragma unroll
  for (int cch = 0; cch < 8; ++cch) {
    const float4 v = arow4[cch*64 + ln];
    const int j0 = cch*256 + ln*4;
    const float vv[4] = {v.x, v.y, v.z, v.w};
#pragma unroll
    for (int q = 0; q < 4; ++q) {
      const unsigned long long m = __ballot(vv[q] > 0.5f);
      if (vv[q] > 0.5f) {
        const int pos = deg + (int)__popcll(m & ((1ull << ln) - 1ull));
        sidx[wv][pos] = (unsigned short)(j0 + q);
      }
      deg += (int)__popcll(m);
    }
  }

  const int col0 = ln, col1 = ln + 64;
  const int h0 = ln >> 5;
  float m0=-1e30f, m1=-1e30f, m2=-1e30f, m3=-1e30f;
  float s0=0.f, s1=0.f, s2=0.f, s3=0.f;
  float acc0=0.f, acc1=0.f;
  for (int base = 0; base < deg; base += 64) {
    const int rem = min(64, deg - base);
    float t0=-1e30f, t1=-1e30f, t2=-1e30f, t3=-1e30f;
    if (ln < rem) {
      const int j = sidx[wv][base + ln];
      const float4 e4 = *(const float4*)(en + (size_t)(b*NN + j)*NH);
      t0 = esi.x + e4.x; t0 = t0 > 0.f ? t0 : 0.2f*t0;
      t1 = esi.y + e4.y; t1 = t1 > 0.f ? t1 : 0.2f*t1;
      t2 = esi.z + e4.z; t2 = t2 > 0.f ? t2 : 0.2f*t2;
      t3 = esi.w + e4.w; t3 = t3 > 0.f ? t3 : 0.2f*t3;
    }
    float c0=t0, c1=t1, c2=t2, c3=t3;
#pragma unroll
    for (int mk = 32; mk >= 1; mk >>= 1) {
      c0 = fmaxf(c0, __shfl_xor(c0, mk));
      c1 = fmaxf(c1, __shfl_xor(c1, mk));
      c2 = fmaxf(c2, __shfl_xor(c2, mk));
      c3 = fmaxf(c3, __shfl_xor(c3, mk));
    }
    const float nm0 = fmaxf(m0,c0), nm1 = fmaxf(m1,c1);
    const float nm2 = fmaxf(m2,c2), nm3 = fmaxf(m3,c3);
    const float r0 = expf(m0-nm0), r1 = expf(m1-nm1);
    const float r2 = expf(m2-nm2), r3 = expf(m3-nm3);
    s0 *= r0; s1 *= r1; s2 *= r2; s3 *= r3;
    float w0=0.f, w1=0.f, w2=0.f, w3=0.f;
    if (ln < rem) {
      w0 = expf(t0-nm0); w1 = expf(t1-nm1);
      w2 = expf(t2-nm2); w3 = expf(t3-nm3);
    }
    float u0=w0, u1=w1, u2=w2, u3=w3;
#pragma unroll
    for (int mk = 32; mk >= 1; mk >>= 1) {
      u0 += __shfl_xor(u0, mk);
      u1 += __shfl_xor(u1, mk);
      u2 += __shfl_xor(u2, mk);
      u3 += __shfl_xor(u3, mk);
    }
    s0 += u0; s1 += u1; s2 += u2; s3 += u3;
    acc0 *= (h0 ? r1 : r0);
    acc1 *= (h0 ? r3 : r2);
    swl[wv][ln][0] = w0; swl[wv][ln][1] = w1;
    swl[wv][ln][2] = w2; swl[wv][ln][3] = w3;
#pragma unroll 4
    for (int k = 0; k < rem; ++k) {
      const int j = sidx[wv][base + k];
      const float* xr = xp + (size_t)(b*NN + j)*128;
      acc0 = fmaf(swl[wv][k][h0],     xr[col0], acc0);
      acc1 = fmaf(swl[wv][k][2 + h0], xr[col1], acc1);
    }
    m0=nm0; m1=nm1; m2=nm2; m3=nm3;
  }
  const float den0 = h0 ? s1 : s0;
  const float den1 = h0 ? s3 : s2;
  cu[(size_t)row*128 + col0] = acc0/den0 + bias[col0];
  cu[(size_t)row*128 + col1] = acc1/den1 + bias[col1];
}

// ---------------------------------------------------------------------------
// k3: fused GRU gates + t = h'@R_p via 3-term split-bf16 MFMA.
// NEW: 256 blocks x 1024 thr (16 waves = 4/SIMD). Wave (jt = w&7, half = w>>3)
// computes HALF the K-range of each GEMM; partials reduced through LDS.
// LDS aliasing (hazard-checked): red zone A [0..16K) = accU slots, later
// rhH/rhL [0..8K) + hpH/hpLo [8K..16K); zone B [16K..32K) = accR/accC/accT.
// 6 barriers. All epilogues on half==0 waves (wave-uniform branch).
// ---------------------------------------------------------------------------
__global__ __launch_bounds__(1024) void k3_mfma(
    const float* __restrict__ cu_, const float* __restrict__ hin,
    const float* __restrict__ bu, const float* __restrict__ br,
    const float* __restrict__ bc,
    const unsigned short* __restrict__ wuh, const unsigned short* __restrict__ wul,
    const unsigned short* __restrict__ wrh, const unsigned short* __restrict__ wrl,
    const unsigned short* __restrict__ wch, const unsigned short* __restrict__ wcl,
    const unsigned short* __restrict__ rph, const unsigned short* __restrict__ rpl,
    float* __restrict__ hp_out,
    __hip_bfloat16* __restrict__ hp_bf, __hip_bfloat16* __restrict__ t_bf)
{
  __shared__ __align__(16) char zH[16*512];   // z hi  [16][256] bf16
  __shared__ __align__(16) char zL[16*512];   // z lo
  __shared__ __align__(16) char red[32768];   // reduction + rh/hp tiles
  char* rhH  = red;            // 4 KB [16][128] bf16 (over consumed accU 0..7)
  char* rhL  = red + 4096;
  char* hpH  = red + 8192;     // over consumed accU slots 8..15
  char* hpLo = red + 12288;
  float* redA = (float*)red;             // accU slots: w*256 + ln*4
  float* redB = (float*)(red + 16384);   // accR / accC / accT slots
  const int t = threadIdx.x;
  const int row0 = blockIdx.x * 16;

  // ---- stage z = [cu | h] as split bf16, swizzled (1024 float4s, 1 iter) ----
  {
    const int q = t;
    const int r = q >> 6;              // row 0..15
    const int c = (q & 63) * 4;        // col 0..252
    float4 v;
    if (c < 128) v = *(const float4*)(cu_ + (size_t)(row0+r)*128 + c);
    else         v = *(const float4*)(hin + (size_t)(row0+r)*128 + (c-128));
    unsigned short hx, lx, hy, ly, hz, lz, hw, lw;
    split2(v.x, hx, lx); split2(v.y, hy, ly);
    split2(v.z, hz, lz); split2(v.w, hw, lw);
    ushort4v h4; h4[0]=hx; h4[1]=hy; h4[2]=hz; h4[3]=hw;
    ushort4v l4; l4[0]=lx; l4[1]=ly; l4[2]=lz; l4[3]=lw;
    const int byte = (c*2) ^ ((r & 7) << 4);
    *(ushort4v*)(zH + r*512 + byte) = h4;
    *(ushort4v*)(zL + r*512 + byte) = l4;
  }
  __syncthreads();                                   // B1

  const int ln = t & 63, w = t >> 6;
  const int jt = w & 7, half = w >> 3;
  const int lr = ln & 15, kid = ln >> 4;
  const int sw = (lr & 7) << 4;
  const int colg = jt*16 + lr;
  const f32x4 zero = {0.f, 0.f, 0.f, 0.f};
  const bf16x8* wuhF = (const bf16x8*)wuh;
  const bf16x8* wulF = (const bf16x8*)wul;
  const bf16x8* wrhF = (const bf16x8*)wrh;
  const bf16x8* wrlF = (const bf16x8*)wrl;
  const bf16x8* wchF = (const bf16x8*)wch;
  const bf16x8* wclF = (const bf16x8*)wcl;
  const bf16x8* rphF = (const bf16x8*)rph;
  const bf16x8* rplF = (const bf16x8*)rpl;

  // ---- u,r partials: ks in [half*4, half*4+4) ----
  f32x4 accU = zero, accR = zero;
#pragma unroll
  for (int i = 0; i < 4; ++i) {
    const int ks = half*4 + i;
    const int kb = ks*64 + kid*16;
    const bf16x8 ah = *(const bf16x8*)(zH + lr*512 + (kb ^ sw));
    const bf16x8 al = *(const bf16x8*)(zL + lr*512 + (kb ^ sw));
    const int fb = (jt*8 + ks)*64 + ln;
    const bf16x8 buH = wuhF[fb];
    const bf16x8 buL = wulF[fb];
    const bf16x8 brH = wrhF[fb];
    const bf16x8 brL = wrlF[fb];
    accU = MFMA_BF16(ah, buH, accU);
    accU = MFMA_BF16(ah, buL, accU);
    accU = MFMA_BF16(al, buH, accU);
    accR = MFMA_BF16(ah, brH, accR);
    accR = MFMA_BF16(ah, brL, accR);
    accR = MFMA_BF16(al, brH, accR);
  }
  *(f32x4*)(redA + w*256 + ln*4) = accU;
  *(f32x4*)(redB + w*256 + ln*4) = accR;
  __syncthreads();                                   // B2

  float hval[4], uval[4];
  if (half == 0) {
    accU += *(const f32x4*)(redA + (w+8)*256 + ln*4);
    accR += *(const f32x4*)(redB + (w+8)*256 + ln*4);
#pragma unroll
    for (int reg = 0; reg < 4; ++reg) {
      const int row16 = kid*4 + reg;
      const int grow = row0 + row16;
      const int nrow = grow & (NN-1);
      const float h_ = hin[(size_t)grow*128 + colg];
      const float uv = 1.f/(1.f + expf(-(bu[nrow] + accU[reg])));
      const float rv = 1.f/(1.f + expf(-(br[nrow] + accR[reg])));
      hval[reg] = h_; uval[reg] = uv;
      unsigned short hs, ls; split2(rv * h_, hs, ls);
      const int byte = (colg*2) ^ ((row16 & 7) << 4);
      *(unsigned short*)(rhH + row16*256 + byte) = hs;
      *(unsigned short*)(rhL + row16*256 + byte) = ls;
    }
  }
  __syncthreads();                                   // B3

  // ---- c partials: half0 -> cu part (z, Wc rows 0..127); half1 -> rh part ----
  f32x4 accC = zero;
#pragma unroll
  for (int i = 0; i < 4; ++i) {
    const int kb = i*64 + kid*16;
    bf16x8 ah, al;
    if (half == 0) {
      ah = *(const bf16x8*)(zH + lr*512 + (kb ^ sw));
      al = *(const bf16x8*)(zL + lr*512 + (kb ^ sw));
    } else {
      ah = *(const bf16x8*)(rhH + lr*256 + (kb ^ sw));
      al = *(const bf16x8*)(rhL + lr*256 + (kb ^ sw));
    }
    const int ks = half*4 + i;
    const int fb = (jt*8 + ks)*64 + ln;
    const bf16x8 bH = wchF[fb];
    const bf16x8 bL = wclF[fb];
    accC = MFMA_BF16(ah, bH, accC);
    accC = MFMA_BF16(ah, bL, accC);
    accC = MFMA_BF16(al, bH, accC);
  }
  *(f32x4*)(redB + w*256 + ln*4) = accC;
  __syncthreads();                                   // B4

  if (half == 0) {
    accC += *(const f32x4*)(redB + (w+8)*256 + ln*4);
#pragma unroll
    for (int reg = 0; reg < 4; ++reg) {
      const int row16 = kid*4 + reg;
      const int grow = row0 + row16;
      const int nrow = grow & (NN-1);
      const float cc = tanhf(bc[nrow] + accC[reg]);
      const float uv = uval[reg];
      const float hpv = uv*hval[reg] + (1.f - uv)*cc;
      hp_out[(size_t)grow*128 + colg] = hpv;
      hp_bf[(size_t)grow*128 + colg] = __float2bfloat16(hpv);
      unsigned short hs, ls; split2(hpv, hs, ls);
      const int byte = (colg*2) ^ ((row16 & 7) << 4);
      *(unsigned short*)(hpH  + row16*256 + byte) = hs;
      *(unsigned short*)(hpLo + row16*256 + byte) = ls;
    }
  }
  __syncthreads();                                   // B5

  // ---- t = h' @ R_p partials: K=128 -> 4 ks, half h does {h*2, h*2+1} ----
  f32x4 accT = zero;
#pragma unroll
  for (int i = 0; i < 2; ++i) {
    const int ks = half*2 + i;
    const int kb = ks*64 + kid*16;
    const bf16x8 ah = *(const bf16x8*)(hpH  + lr*256 + (kb ^ sw));
    const bf16x8 al = *(const bf16x8*)(hpLo + lr*256 + (kb ^ sw));
    const int fb = (jt*4 + ks)*64 + ln;
    const bf16x8 bH = rphF[fb];
    const bf16x8 bL = rplF[fb];
    accT = MFMA_BF16(ah, bH, accT);
    accT = MFMA_BF16(ah, bL, accT);
    accT = MFMA_BF16(al, bH, accT);
  }
  *(f32x4*)(redB + w*256 + ln*4) = accT;
  __syncthreads();                                   // B6

  if (half == 0) {
    accT += *(const f32x4*)(redB + (w+8)*256 + ln*4);
#pragma unroll
    for (int reg = 0; reg < 4; ++reg) {
      const int grow = row0 + kid*4 + reg;
      t_bf[(size_t)grow*128 + colg] = __float2bfloat16(accT[reg]);
    }
  }
}

// ---------------------------------------------------------------------------
// k4b: A[b] = t[b] @ hp[b]^T via bf16 MFMA + LDS-transposed coalesced
// writeout. (unchanged from r11)
// ---------------------------------------------------------------------------
__global__ __launch_bounds__(256) void k4b_dec(
    const __hip_bfloat16* __restrict__ t_bf,
    const __hip_bfloat16* __restrict__ hp_bf,
    float* __restrict__ A)
{
  __shared__ __align__(16) char smem[128*132*4];  // 67.5 KB
  char* Alds = smem;
  char* Blds = smem + 32768;
  float* Cst = (float*)smem;
  const int t = threadIdx.x;
  const int ln = t & 63, wv = t >> 6;
  const int b = blockIdx.z;
  const int i0 = blockIdx.y * 128, j0 = blockIdx.x * 128;

  {
    const int sub = ln >> 4;
    const int cb  = (ln & 15) * 16;
#pragma unroll
    for (int q = 0; q < 8; ++q) {
      const int chunk = wv*8 + q;
      const int row = chunk*4 + sub;
      const int scb = cb ^ ((row & 7) << 4);
      const ushort8 va = *(const ushort8*)
          ((const char*)(t_bf + ((size_t)(b*NN) + i0 + row)*128) + cb);
      *(ushort8*)(Alds + row*256 + scb) = va;
      const ushort8 vb = *(const ushort8*)
          ((const char*)(hp_bf + ((size_t)(b*NN) + j0 + row)*128) + cb);
      *(ushort8*)(Blds + row*256 + scb) = vb;
    }
  }
  __syncthreads();

  const int wr = wv >> 1, wc = wv & 1;
  const int lrow = ln & 15;
  const int kid  = ln >> 4;
  f32x4 acc[4][4];
  const f32x4 zero = {0.f, 0.f, 0.f, 0.f};
#pragma unroll
  for (int m = 0; m < 4; ++m)
#pragma unroll
    for (int n = 0; n < 4; ++n) acc[m][n] = zero;

#pragma unroll
  for (int ks = 0; ks < 4; ++ks) {
    const int kb = ks*64 + kid*16;
    bf16x8 af[4], bfr[4];
#pragma unroll
    for (int m = 0; m < 4; ++m) {
      const int arow = wr*64 + m*16 + lrow;
      af[m] = *(const bf16x8*)(Alds + arow*256 + (kb ^ ((arow & 7) << 4)));
      const int brow = wc*64 + m*16 + lrow;
      bfr[m] = *(const bf16x8*)(Blds + brow*256 + (kb ^ ((brow & 7) << 4)));
    }
#pragma unroll
    for (int m = 0; m < 4; ++m)
#pragma unroll
      for (int n = 0; n < 4; ++n)
        acc[m][n] = MFMA_BF16(af[m], bfr[n], acc[m][n]);
  }
  __syncthreads();

#pragma unroll
  for (int m = 0; m < 4; ++m) {
    const int crow = wr*64 + m*16 + kid*4;
#pragma unroll
    for (int n = 0; n < 4; ++n) {
      const int ccol = wc*64 + n*16 + lrow;
#pragma unroll
      for (int r = 0; r < 4; ++r)
        Cst[(crow + r)*132 + ccol] = acc[m][n][r];
    }
  }
  __syncthreads();

#pragma unroll
  for (int p = 0; p < 16; ++p) {
    const int row = p*8 + (t >> 5);
    const int c4  = (t & 31) * 4;
    const float4 v = *(const float4*)&Cst[row*132 + c4];
    *(float4*)(A + ((size_t)b*NN + i0 + row)*NN + j0 + c4) = v;
  }
}

// ---------------------------------------------------------------------------
extern "C" void kernel_launch(void* const* d_in, const int* in_sizes, int n_in,
                              void* d_out, int out_size, void* d_ws, size_t ws_size,
                              hipStream_t stream)
{
  const float* x    = (const float*)d_in[0];
  const float* a    = (const float*)d_in[1];
  const float* h    = (const float*)d_in[2];
  const float* kern = (const float*)d_in[3];
  const float* as_  = (const float*)d_in[4];
  const float* an_  = (const float*)d_in[5];
  const float* bias = (const float*)d_in[6];
  const float* bu   = (const float*)d_in[7];
  const float* br   = (const float*)d_in[8];
  const float* bc   = (const float*)d_in[9];
  const float* Wu   = (const float*)d_in[10];
  const float* Wr   = (const float*)d_in[11];
  const float* Wc   = (const float*)d_in[12];
  const float* Rp   = (const float*)d_in[13];
  (void)in_sizes; (void)n_in; (void)out_size; (void)ws_size;

  float* ws = (float*)d_ws;
  float* xp = ws + XP_OFF;
  float* es = ws + ES_OFF;
  float* en = ws + EN_OFF;
  float* cu = ws + CU_OFF;
  __hip_bfloat16* t_bf  = (__hip_bfloat16*)(ws + TBF_OFF);
  __hip_bfloat16* hp_bf = (__hip_bfloat16*)(ws + HPBF_OFF);
  unsigned short* wuh = (unsigned short*)(ws + WUH_OFF);
  unsigned short* wul = (unsigned short*)(ws + WUL_OFF);
  unsigned short* wrh = (unsigned short*)(ws + WRH_OFF);
  unsigned short* wrl = (unsigned short*)(ws + WRL_OFF);
  unsigned short* wch = (unsigned short*)(ws + WCH_OFF);
  unsigned short* wcl = (unsigned short*)(ws + WCL_OFF);
  unsigned short* rph = (unsigned short*)(ws + RPH_OFF);
  unsigned short* rpl = (unsigned short*)(ws + RPL_OFF);

  float* A  = (float*)d_out;
  float* hp = (float*)d_out + A_ELEMS;

  hipLaunchKernelGGL(k01_prep_xp, dim3(448 + ROWS_TOT/8), dim3(256), 0, stream,
                     Wu, Wr, Wc, Rp, wuh, wul, wrh, wrl, wch, wcl, rph, rpl,
                     x, kern, as_, an_, xp, es, en);
  hipLaunchKernelGGL(k2_attn, dim3(ROWS_TOT/4), dim3(256), 0, stream,
                     a, xp, es, en, bias, cu);
  hipLaunchKernelGGL(k3_mfma, dim3(ROWS_TOT/16), dim3(1024), 0, stream,
                     cu, h, bu, br, bc, wuh, wul, wrh, wrl, wch, wcl, rph, rpl,
                     hp, hp_bf, t_bf);
  hipLaunchKernelGGL(k4b_dec, dim3(NN/128, NN/128, NB), dim3(256), 0, stream,
                     t_bf, hp_bf, A);
}